// Round 9
// baseline (286.151 us; speedup 1.0000x reference)
//
#include <hip/hip_runtime.h>
#include <hip/hip_bf16.h>

// Problem dims (fixed by setup_inputs)
#define NB 32
#define CC 1024
#define SS 1568            // T*H*W = 32*7*7
#define KK 128
#define NCOL 448           // 32 n * 14 s-blocks of 112
#define EPSV 1e-5f
#define XP_P 132           // LDS transpose pitch (floats)
#define NSB3 224           // gram blocks (224 s-rows each; 224*224 = 50176)

typedef __attribute__((ext_vector_type(8))) short bf16x8;
typedef __attribute__((ext_vector_type(4))) short bf16x4v;
typedef __attribute__((ext_vector_type(4))) float f32x4;

__device__ __forceinline__ unsigned short f2bf(float f) {
  union { float f; unsigned u; } v; v.f = f;
  return (unsigned short)((v.u + 0x7fffu + ((v.u >> 16) & 1u)) >> 16);
}
__device__ __forceinline__ float bf2f(unsigned short h) {
  union { unsigned u; float f; } v; v.u = ((unsigned)h) << 16; return v.f;
}

// ---- fused bn1 partial stats + x transpose to xT_sw (fragment-major bf16) ----
// grid (14 sb, 16 cc, 32 n), 512 threads.
// Wave 7 (t>=448) does stats (1 thread/c, 28 conflict-free b128 LDS reads),
// overlapping waves 0..6 doing the transpose. No serialized stats phase.
// xT_sw elem (n,s,c) at:
//   n*1605632 + ((s>>4)*32 + (c>>5))*512 + (s&15)*32 + ((c>>3)&3)*8 + (c&7)
__global__ __launch_bounds__(512) void xpose_stats(
    const float* __restrict__ x, unsigned short* __restrict__ xT,
    float* __restrict__ p1s, float* __restrict__ p1q) {
  __shared__ float lt[64 * XP_P];  // 33792 B; 4 blocks/CU = 32 waves/CU
  int sb = blockIdx.x, cc = blockIdx.y, n = blockIdx.z;
  int t = threadIdx.x;
  int s0 = sb * 112, c0 = cc * 64;
  const float* xp = x + ((size_t)n * CC + c0) * SS + s0;
  #pragma unroll
  for (int j = 0; j < 4; j++) {
    int idx = t + 512 * j;
    if (idx < 1792) {
      int r = idx / 28, q = idx % 28;
      float4 v = *(const float4*)(xp + (size_t)r * SS + 4 * q);
      *(float4*)&lt[r * XP_P + 4 * (q ^ (r >> 3))] = v;
    }
  }
  __syncthreads();
  if (t >= 448) {
    // stats wave: one thread per c-row
    int r = t - 448;
    float s = 0.f, sq = 0.f;
    #pragma unroll
    for (int b = 0; b < 28; b++) {
      float4 v = *(const float4*)&lt[r * XP_P + 4 * (b ^ (r >> 3))];
      s  += v.x + v.y + v.z + v.w;
      sq += v.x * v.x + v.y * v.y + v.z * v.z + v.w * v.w;
    }
    int col = n * 14 + sb;
    p1s[(size_t)(c0 + r) * NCOL + col] = s;
    p1q[(size_t)(c0 + r) * NCOL + col] = sq;
  } else {
    // transpose write: fragment-major
    int co = t & 7, sl = t >> 3;   // sl 0..55
    #pragma unroll
    for (int j = 0; j < 2; j++) {
      int sloc = sl + 56 * j;
      int s = s0 + sloc;
      bf16x8 pk;
      #pragma unroll
      for (int i = 0; i < 8; i++) {
        int r = co * 8 + i;
        pk[i] = (short)f2bf(lt[r * XP_P + 4 * ((sloc >> 2) ^ co) + (sloc & 3)]);
      }
      size_t off = (size_t)n * 1605632 +
                   (size_t)((s >> 4) * 32 + (cc * 2 + (co >> 2))) * 512 +
                   (s & 15) * 32 + (co & 3) * 8;
      *(bf16x8*)(xT + off) = pk;
    }
  }
}

// ---- merged: blocks 0..127 = bn2+nh-write; blocks 128..159 = bn1 finalize ----
__global__ void prep_stats(const float* __restrict__ nodes, const float* __restrict__ g2,
                           const float* __restrict__ b2, unsigned short* __restrict__ nh,
                           const float* __restrict__ p1s, const float* __restrict__ p1q,
                           const float* __restrict__ g1, const float* __restrict__ b1,
                           float* a1, float* c1) {
  __shared__ float sred[4][8][2];
  __shared__ float bc[8][2];
  __shared__ float red1[4][32][2];
  int t = threadIdx.x, w = t >> 6;
  if (blockIdx.x < 128) {
    int blk = blockIdx.x;
    int cl = t & 7, kq = t >> 3;
    int c = blk * 8 + cl;
    float s = 0.f, sq = 0.f;
    #pragma unroll
    for (int i = 0; i < 4; i++) {
      float v = nodes[(size_t)(kq + 32 * i) * CC + c];
      s += v; sq += v * v;
    }
    s += __shfl_xor(s, 8);  sq += __shfl_xor(sq, 8);
    s += __shfl_xor(s, 16); sq += __shfl_xor(sq, 16);
    s += __shfl_xor(s, 32); sq += __shfl_xor(sq, 32);
    if ((t & 63) < 8) { sred[w][cl][0] = s; sred[w][cl][1] = sq; }
    __syncthreads();
    if (t < 8) {
      float st = sred[0][t][0] + sred[1][t][0] + sred[2][t][0] + sred[3][t][0];
      float qt = sred[0][t][1] + sred[1][t][1] + sred[2][t][1] + sred[3][t][1];
      float inv = 1.f / (float)KK;
      float m = st * inv, var = qt * inv - m * m;
      float r = rsqrtf(var + EPSV);
      float a = g2[blk * 8 + t] * r;
      bc[t][0] = a; bc[t][1] = b2[blk * 8 + t] - m * a;
    }
    __syncthreads();
    float a = bc[cl][0], cc2 = bc[cl][1];
    #pragma unroll
    for (int i = 0; i < 4; i++) {
      int k = kq + 32 * i;
      nh[(size_t)k * CC + c] = f2bf(nodes[(size_t)k * CC + c] * a + cc2);
    }
  } else {
    int blk = blockIdx.x - 128;
    int cl = t & 31, part = t >> 5;
    int c = blk * 32 + cl;
    const float4* ps = (const float4*)(p1s + (size_t)c * NCOL + part * 56);
    const float4* pq = (const float4*)(p1q + (size_t)c * NCOL + part * 56);
    float s = 0.f, sq = 0.f;
    #pragma unroll
    for (int i = 0; i < 14; i++) {
      float4 v = ps[i]; s += v.x + v.y + v.z + v.w;
      float4 u = pq[i]; sq += u.x + u.y + u.z + u.w;
    }
    s += __shfl_xor(s, 32); sq += __shfl_xor(sq, 32);
    if ((t & 63) < 32) { red1[w][cl][0] = s; red1[w][cl][1] = sq; }
    __syncthreads();
    if (t < 32) {
      float st = red1[0][t][0] + red1[1][t][0] + red1[2][t][0] + red1[3][t][0];
      float qt = red1[0][t][1] + red1[1][t][1] + red1[2][t][1] + red1[3][t][1];
      float inv = 1.f / ((float)NB * SS);
      float m = st * inv, var = qt * inv - m * m;
      float r = rsqrtf(var + EPSV);
      float a = g1[c] * r;
      a1[c] = a; c1[c] = b1[c] - m * a;
    }
  }
}

// ---- linear via MFMA (inline W cvt): grid (32 jt, 2 mt) ----
__global__ __launch_bounds__(256) void linear_mfma(
    const unsigned short* __restrict__ nh, const float* __restrict__ Wm,
    const float* __restrict__ bW, float* __restrict__ Lb) {
  int jt = blockIdx.x, mt = blockIdx.y;
  int t = threadIdx.x, w = t >> 6, lane = t & 63, g = lane >> 4, l15 = lane & 15;
  int krow = mt * 64 + w * 16 + l15;
  f32x4 acc[2];
  acc[0] = (f32x4){0.f,0.f,0.f,0.f}; acc[1] = (f32x4){0.f,0.f,0.f,0.f};
  #pragma unroll 4
  for (int c0 = 0; c0 < CC; c0 += 32) {
    bf16x8 af = *(const bf16x8*)(nh + (size_t)krow * CC + c0 + g * 8);
    #pragma unroll
    for (int nf = 0; nf < 2; nf++) {
      const float* wr = Wm + (size_t)(jt * 32 + nf * 16 + l15) * CC + c0 + g * 8;
      float4 v0 = *(const float4*)wr, v1 = *(const float4*)(wr + 4);
      bf16x8 bfr;
      bfr[0] = (short)f2bf(v0.x); bfr[1] = (short)f2bf(v0.y);
      bfr[2] = (short)f2bf(v0.z); bfr[3] = (short)f2bf(v0.w);
      bfr[4] = (short)f2bf(v1.x); bfr[5] = (short)f2bf(v1.y);
      bfr[6] = (short)f2bf(v1.z); bfr[7] = (short)f2bf(v1.w);
      acc[nf] = __builtin_amdgcn_mfma_f32_16x16x32_bf16(af, bfr, acc[nf], 0, 0, 0);
    }
  }
  #pragma unroll
  for (int nf = 0; nf < 2; nf++) {
    int j = jt * 32 + nf * 16 + l15;
    float bwv = bW[j];
    #pragma unroll
    for (int r = 0; r < 4; r++)
      Lb[(size_t)(mt * 64 + w * 16 + g * 4 + r) * CC + j] = acc[nf][r] + bwv;
  }
}

// ---- bn3 + pack frag-major ndA2_sw, Mt_sw, plain Mt_lin, Cst ----
__global__ void bn3_pack(const float* __restrict__ Lb, const float* __restrict__ g3,
                         const float* __restrict__ b3, const float* __restrict__ loc,
                         const float* __restrict__ a1, const float* __restrict__ c1,
                         unsigned short* __restrict__ ndA2, unsigned short* __restrict__ Mt,
                         unsigned short* __restrict__ MtL, float* __restrict__ Cst) {
  __shared__ float red[8];
  int k = blockIdx.x, t = threadIdx.x, w = t >> 6;
  float vv[4];
  float s = 0.f, sq = 0.f;
  for (int i = 0; i < 4; i++) {
    float v = Lb[(size_t)k * CC + t + 256 * i];
    vv[i] = v; s += v; sq += v * v;
  }
  for (int m = 1; m < 64; m <<= 1) { s += __shfl_xor(s, m); sq += __shfl_xor(sq, m); }
  if ((t & 63) == 0) { red[w] = s; red[4 + w] = sq; }
  __syncthreads();
  s  = red[0] + red[1] + red[2] + red[3];
  sq = red[4] + red[5] + red[6] + red[7];
  float inv = 1.f / (float)CC;
  float m3 = s * inv, var = sq * inv - m3 * m3;
  float r = rsqrtf(var + EPSV);
  float a = g3[k] * r, cc3 = b3[k] - m3 * a;
  float lv = loc[0];
  float gate = 1.f / (1.f + __expf(-lv)) * 1.2f - 0.1f;
  gate = fminf(fmaxf(gate, 0.f), 1.f);
  float cs = 0.f;
  for (int i = 0; i < 4; i++) {
    int j = t + 256 * i;
    float nd = vv[i] * a + cc3;
    unsigned short ndb = f2bf(nd * a1[j]);
    unsigned short mtb = f2bf(gate * nd);
    ndA2[(size_t)((k >> 4) * 32 + (j >> 5)) * 512 + (k & 15) * 32 + ((j >> 3) & 3) * 8 + (j & 7)] = ndb;
    Mt[(size_t)((j >> 4) * 4 + (k >> 5)) * 512 + (j & 15) * 32 + ((k >> 3) & 3) * 8 + (k & 7)] = mtb;
    MtL[(size_t)j * KK + k] = mtb;
    cs += c1[j] * nd;
  }
  for (int m = 1; m < 64; m <<= 1) cs += __shfl_xor(cs, m);
  __syncthreads();
  if ((t & 63) == 0) red[w] = cs;
  __syncthreads();
  if (t == 0) Cst[k] = red[0] + red[1] + red[2] + red[3];
}

// ---- GEMM1: frag-major streaming; G[n][s][k] -> GT_sw frag-major ----
__global__ __launch_bounds__(256) void gemm1(
    const unsigned short* __restrict__ ndA2, const unsigned short* __restrict__ xT,
    const float* __restrict__ Cst, unsigned short* __restrict__ GT) {
  int sb = blockIdx.x;               // 49 (s-tiles of 32)
  int n  = blockIdx.y;
  int t = threadIdx.x, w = t >> 6, lane = t & 63, g = lane >> 4, l15 = lane & 15;
  f32x4 acc[2][2];
  for (int m = 0; m < 2; m++)
    for (int nf = 0; nf < 2; nf++) acc[m][nf] = (f32x4){0.f, 0.f, 0.f, 0.f};
  int lofs = l15 * 32 + g * 8;
  const unsigned short* xb = xT + (size_t)n * 1605632;
  #pragma unroll 8
  for (int cc2 = 0; cc2 < 32; cc2++) {
    bf16x8 af[2], bfr[2];
    #pragma unroll
    for (int m = 0; m < 2; m++)
      af[m] = *(const bf16x8*)(ndA2 + (size_t)((w * 2 + m) * 32 + cc2) * 512 + lofs);
    #pragma unroll
    for (int nf = 0; nf < 2; nf++)
      bfr[nf] = *(const bf16x8*)(xb + (size_t)((sb * 2 + nf) * 32 + cc2) * 512 + lofs);
    #pragma unroll
    for (int m = 0; m < 2; m++)
      #pragma unroll
      for (int nf = 0; nf < 2; nf++)
        acc[m][nf] = __builtin_amdgcn_mfma_f32_16x16x32_bf16(af[m], bfr[nf], acc[m][nf], 0, 0, 0);
  }
  unsigned short* gtn = GT + (size_t)n * 200704;
  #pragma unroll
  for (int nf = 0; nf < 2; nf++) {
    #pragma unroll
    for (int m = 0; m < 2; m++) {
      int kb = w * 32 + m * 16 + g * 4;
      float4 cst = *(const float4*)(Cst + kb);
      bf16x4v ov;
      ov[0] = (short)f2bf(acc[m][nf][0] + cst.x);
      ov[1] = (short)f2bf(acc[m][nf][1] + cst.y);
      ov[2] = (short)f2bf(acc[m][nf][2] + cst.z);
      ov[3] = (short)f2bf(acc[m][nf][3] + cst.w);
      int g2 = m * 2 + (g >> 1);
      int e0 = (g & 1) * 4;
      *(bf16x4v*)(gtn + (size_t)((sb * 2 + nf) * 4 + w) * 512 + l15 * 32 + g2 * 8 + e0) = ov;
    }
  }
}

// ---- Gram of G: fp32 LDS (convert once). part[b][k1*128+k2], part[b][16384+k]=rowsum ----
__global__ __launch_bounds__(256) void gram(const unsigned short* __restrict__ GT,
                                            float* __restrict__ part) {
  __shared__ float lf[112 * 128];   // 57344 B
  int b = blockIdx.x, t = threadIdx.x;
  int k1b = t >> 4, k2b = t & 15;
  float acc[8][8];
  float gsum[8];
  #pragma unroll
  for (int i = 0; i < 8; i++) {
    gsum[i] = 0.f;
    #pragma unroll
    for (int j = 0; j < 8; j++) acc[i][j] = 0.f;
  }
  for (int chunk = 0; chunk < 2; chunk++) {
    int St0 = b * 14 + chunk * 7;
    #pragma unroll
    for (int it = 0; it < 7; it++) {
      int u = t + 256 * it;              // 1792 16B-units
      int Stl = u >> 8, rem = u & 255;
      bf16x8 v = *(const bf16x8*)(GT + (size_t)(St0 + Stl) * 2048 + rem * 8);
      int sl = Stl * 16 + ((rem & 63) >> 2);
      int kk = (rem >> 6) * 32 + (rem & 3) * 8;
      float4 f0, f1;
      f0.x = bf2f((unsigned short)v[0]); f0.y = bf2f((unsigned short)v[1]);
      f0.z = bf2f((unsigned short)v[2]); f0.w = bf2f((unsigned short)v[3]);
      f1.x = bf2f((unsigned short)v[4]); f1.y = bf2f((unsigned short)v[5]);
      f1.z = bf2f((unsigned short)v[6]); f1.w = bf2f((unsigned short)v[7]);
      *(float4*)&lf[sl * 128 + kk] = f0;
      *(float4*)&lf[sl * 128 + kk + 4] = f1;
    }
    __syncthreads();
    for (int sl = 0; sl < 112; sl++) {
      float4 a0 = *(const float4*)&lf[sl * 128 + k1b * 8];
      float4 a1 = *(const float4*)&lf[sl * 128 + k1b * 8 + 4];
      float4 b0 = *(const float4*)&lf[sl * 128 + k2b * 8];
      float4 b1 = *(const float4*)&lf[sl * 128 + k2b * 8 + 4];
      float a[8]  = {a0.x, a0.y, a0.z, a0.w, a1.x, a1.y, a1.z, a1.w};
      float bb[8] = {b0.x, b0.y, b0.z, b0.w, b1.x, b1.y, b1.z, b1.w};
      #pragma unroll
      for (int i = 0; i < 8; i++)
        #pragma unroll
        for (int j = 0; j < 8; j++) acc[i][j] += a[i] * bb[j];
      if (k1b == 0) {
        #pragma unroll
        for (int j = 0; j < 8; j++) gsum[j] += bb[j];
      }
    }
    __syncthreads();
  }
  float* pb = part + (size_t)b * 16512;
  #pragma unroll
  for (int i = 0; i < 8; i++) {
    int k1 = k1b * 8 + i;
    *(float4*)(pb + k1 * 128 + k2b * 8)     = (float4){acc[i][0], acc[i][1], acc[i][2], acc[i][3]};
    *(float4*)(pb + k1 * 128 + k2b * 8 + 4) = (float4){acc[i][4], acc[i][5], acc[i][6], acc[i][7]};
  }
  if (k1b == 0) {
    *(float4*)(pb + 16384 + k2b * 8)     = (float4){gsum[0], gsum[1], gsum[2], gsum[3]};
    *(float4*)(pb + 16384 + k2b * 8 + 4) = (float4){gsum[4], gsum[5], gsum[6], gsum[7]};
  }
}

// ---- reduce 224 gram partials -> 4 partials ----
__global__ void gram_reduceA(const float* __restrict__ part, float* __restrict__ partB) {
  int e = blockIdx.x * 256 + threadIdx.x;
  if (e >= 16512) return;
  int p0 = blockIdx.y * 56;
  float s = 0.f;
  #pragma unroll 8
  for (int p = p0; p < p0 + 56; p++) s += part[(size_t)p * 16512 + e];
  partB[(size_t)blockIdx.y * 16512 + e] = s;
}

// ---- bn6 stats from 4 partB: a6[c], c6[c]. grid 128 x 256 (8 c per block) ----
__global__ __launch_bounds__(256) void bn6stats(
    const float* __restrict__ partB, const unsigned short* __restrict__ MtL,
    const float* __restrict__ g6, const float* __restrict__ b6,
    float* a6, float* c6) {
  __shared__ float covL[16384];   // 64 KB
  __shared__ float mL[8 * 128];
  __shared__ float gbL[128];
  int b = blockIdx.x, t = threadIdx.x;
  int c0 = b * 8;
  #pragma unroll
  for (int i = 0; i < 16; i++) {
    int u = (t + 256 * i) * 4;
    float4 va = *(const float4*)(partB + u);
    float4 vb = *(const float4*)(partB + 16512 + u);
    float4 vc = *(const float4*)(partB + 2 * 16512 + u);
    float4 vd = *(const float4*)(partB + 3 * 16512 + u);
    *(float4*)&covL[u] = (float4){va.x + vb.x + vc.x + vd.x, va.y + vb.y + vc.y + vd.y,
                                  va.z + vb.z + vc.z + vd.z, va.w + vb.w + vc.w + vd.w};
  }
  if (t < 128) {
    int row = t >> 4, unit = t & 15;
    bf16x8 v = *(const bf16x8*)(MtL + (size_t)(c0 + row) * KK + unit * 8);
    #pragma unroll
    for (int j = 0; j < 8; j++) mL[row * 128 + unit * 8 + j] = bf2f((unsigned short)v[j]);
  }
  if (t < 32) {
    int u = 16384 + t * 4;
    float4 va = *(const float4*)(partB + u);
    float4 vb = *(const float4*)(partB + 16512 + u);
    float4 vc = *(const float4*)(partB + 2 * 16512 + u);
    float4 vd = *(const float4*)(partB + 3 * 16512 + u);
    *(float4*)&gbL[t * 4] = (float4){va.x + vb.x + vc.x + vd.x, va.y + vb.y + vc.y + vd.y,
                                     va.z + vb.z + vc.z + vd.z, va.w + vb.w + vc.w + vd.w};
  }
  __syncthreads();
  int cl = t >> 5, kq = t & 31;
  float4 m4 = *(const float4*)&mL[cl * 128 + kq * 4];
  float4 g4 = *(const float4*)&gbL[kq * 4];
  float mv = m4.x * g4.x + m4.y * g4.y + m4.z * g4.z + m4.w * g4.w;
  float vv = 0.f;
  for (int k = 0; k < 128; k++) {
    float4 c4 = *(const float4*)&covL[k * 128 + kq * 4];
    float mk = mL[cl * 128 + k];
    vv += mk * (c4.x * m4.x + c4.y * m4.y + c4.z * m4.z + c4.w * m4.w);
  }
  for (int msk = 1; msk < 32; msk <<= 1) { mv += __shfl_xor(mv, msk); vv += __shfl_xor(vv, msk); }
  if (kq == 0) {
    int c = c0 + cl;
    float inv = 1.f / ((float)NB * SS);
    float mean = mv * inv, var = vv * inv - mean * mean;
    float r = rsqrtf(var + EPSV);
    float a = g6[c] * r;
    a6[c] = a; c6[c] = b6[c] - mean * a;
  }
}

// ---- GEMM2: XCD-swizzled; swapped-operand MFMA -> C[s][c]; f32x4 NT stores ----
__global__ __launch_bounds__(256) void gemm2(
    const unsigned short* __restrict__ Mt, const unsigned short* __restrict__ GT,
    const float* __restrict__ a6, const float* __restrict__ c6,
    float* __restrict__ out) {
  // decode: all 8 ct-blocks of a (sb,n) pair share id%8 -> same XCD -> GT tile fetched once
  int id = blockIdx.x;
  int xcd = id & 7;
  int mid = id >> 3;          // 0..447
  int ct  = mid & 7;
  int p   = (mid >> 3) * 8 + xcd;   // pair 0..447
  int sb  = p % 14, n = p / 14;
  int t = threadIdx.x, w = t >> 6, lane = t & 63, g = lane >> 4, l15 = lane & 15;
  f32x4 acc[7][2];
  for (int nf = 0; nf < 7; nf++)
    for (int m = 0; m < 2; m++) acc[nf][m] = (f32x4){0.f, 0.f, 0.f, 0.f};
  int lofs = l15 * 32 + g * 8;
  const unsigned short* gtb = GT + (size_t)n * 200704;
  #pragma unroll
  for (int ks = 0; ks < 4; ks++) {
    bf16x8 af[2];
    #pragma unroll
    for (int m = 0; m < 2; m++)
      af[m] = *(const bf16x8*)(Mt + (size_t)((ct * 8 + w * 2 + m) * 4 + ks) * 512 + lofs);
    #pragma unroll
    for (int nf = 0; nf < 7; nf++) {
      bf16x8 bfr = *(const bf16x8*)(gtb + (size_t)((sb * 7 + nf) * 4 + ks) * 512 + lofs);
      #pragma unroll
      for (int m = 0; m < 2; m++)
        acc[nf][m] = __builtin_amdgcn_mfma_f32_16x16x32_bf16(bfr, af[m], acc[nf][m], 0, 0, 0);
    }
  }
  // epilogue: C[i=s][j=c]; thread's 4 regs = 4 consecutive s in one c-row -> f32x4 NT store
  float a_[2], cc_[2];
  size_t rowbase[2];
  #pragma unroll
  for (int m = 0; m < 2; m++) {
    int c = ct * 128 + w * 32 + m * 16 + l15;
    a_[m] = a6[c]; cc_[m] = c6[c];
    rowbase[m] = ((size_t)(n * CC + c)) * SS;
  }
  #pragma unroll
  for (int nf = 0; nf < 7; nf++) {
    int s4 = sb * 112 + nf * 16 + g * 4;
    #pragma unroll
    for (int m = 0; m < 2; m++) {
      f32x4 ov;
      float v0 = acc[nf][m][0] * a_[m] + cc_[m];
      float v1 = acc[nf][m][1] * a_[m] + cc_[m];
      float v2 = acc[nf][m][2] * a_[m] + cc_[m];
      float v3 = acc[nf][m][3] * a_[m] + cc_[m];
      ov[0] = v0 >= 0.f ? v0 : 0.2f * v0;
      ov[1] = v1 >= 0.f ? v1 : 0.2f * v1;
      ov[2] = v2 >= 0.f ? v2 : 0.2f * v2;
      ov[3] = v3 >= 0.f ? v3 : 0.2f * v3;
      __builtin_nontemporal_store(ov, (f32x4*)&out[rowbase[m] + s4]);
    }
  }
}

extern "C" void kernel_launch(void* const* d_in, const int* in_sizes, int n_in,
                              void* d_out, int out_size, void* d_ws, size_t ws_size,
                              hipStream_t stream) {
  const float* x     = (const float*)d_in[0];
  const float* nodes = (const float*)d_in[1];
  const float* g1 = (const float*)d_in[2];
  const float* b1 = (const float*)d_in[3];
  const float* g2 = (const float*)d_in[4];
  const float* b2 = (const float*)d_in[5];
  const float* g3 = (const float*)d_in[6];
  const float* b3 = (const float*)d_in[7];
  const float* Wm = (const float*)d_in[8];
  const float* bW = (const float*)d_in[9];
  const float* loc = (const float*)d_in[10];
  const float* g6 = (const float*)d_in[11];
  const float* b6 = (const float*)d_in[12];
  float* out = (float*)d_out;
  char* ws = (char*)d_ws;

  float* p1s = (float*)(ws + 0);                           // 1,835,008
  float* p1q = (float*)(ws + 1835008);                     // 1,835,008
  float* a1  = (float*)(ws + 3670016);
  float* c1  = (float*)(ws + 3674112);
  float* Cst = (float*)(ws + 3678208);                     // 512 (pad 4096)
  unsigned short* nh   = (unsigned short*)(ws + 3682304);  // 262,144
  float* Lb  = (float*)(ws + 3944448);                     // 524,288
  unsigned short* ndA2 = (unsigned short*)(ws + 4468736);  // 262,144
  unsigned short* Mt   = (unsigned short*)(ws + 4730880);  // 262,144
  unsigned short* MtL  = (unsigned short*)(ws + 4993024);  // 262,144
  float* a6  = (float*)(ws + 5255168);
  float* c6  = (float*)(ws + 5259264);
  float* gramP = (float*)(ws + 5329920);                   // 14,794,752
  unsigned short* GT = (unsigned short*)(ws + 20124672);   // 12,845,056
  unsigned short* xT = (unsigned short*)(ws + 32969728);   // 102,760,448
  float* partB = (float*)(ws + 135730176);                 // 264,192 -> end ~136 MB

  xpose_stats<<<dim3(14, 16, NB), dim3(512), 0, stream>>>(x, xT, p1s, p1q);
  prep_stats<<<dim3(160), dim3(256), 0, stream>>>(nodes, g2, b2, nh, p1s, p1q, g1, b1, a1, c1);
  linear_mfma<<<dim3(32, 2), dim3(256), 0, stream>>>(nh, Wm, bW, Lb);
  bn3_pack<<<dim3(KK), dim3(256), 0, stream>>>(Lb, g3, b3, loc, a1, c1, ndA2, Mt, MtL, Cst);
  gemm1<<<dim3(49, NB), dim3(256), 0, stream>>>(ndA2, xT, Cst, GT);
  gram<<<dim3(NSB3), dim3(256), 0, stream>>>(GT, gramP);
  gram_reduceA<<<dim3(65, 4), dim3(256), 0, stream>>>(gramP, partB);
  bn6stats<<<dim3(128), dim3(256), 0, stream>>>(partB, MtL, g6, b6, a6, c6);
  gemm2<<<dim3(3584), dim3(256), 0, stream>>>(Mt, GT, a6, c6, out);
}

// Round 10
// 284.723 us; speedup vs baseline: 1.0050x; 1.0050x over previous
//
#include <hip/hip_runtime.h>
#include <hip/hip_bf16.h>

// Problem dims (fixed by setup_inputs)
#define NB 32
#define CC 1024
#define SS 1568            // T*H*W = 32*7*7
#define KK 128
#define NCOL 448           // 32 n * 14 s-blocks of 112
#define EPSV 1e-5f
#define XP_P 132           // LDS transpose pitch (floats)
#define NSB3 224           // gram blocks (224 s-rows each; 224*224 = 50176)

typedef __attribute__((ext_vector_type(8))) short bf16x8;
typedef __attribute__((ext_vector_type(4))) short bf16x4v;
typedef __attribute__((ext_vector_type(4))) float f32x4;

__device__ __forceinline__ unsigned short f2bf(float f) {
  union { float f; unsigned u; } v; v.f = f;
  return (unsigned short)((v.u + 0x7fffu + ((v.u >> 16) & 1u)) >> 16);
}
__device__ __forceinline__ float bf2f(unsigned short h) {
  union { unsigned u; float f; } v; v.u = ((unsigned)h) << 16; return v.f;
}

// ---- fused bn1 partial stats + x transpose to xT_sw (fragment-major bf16) ----
// grid (14 sb, 16 cc, 32 n), 512 threads. (r7-proven version)
// xT_sw elem (n,s,c) at:
//   n*1605632 + ((s>>4)*32 + (c>>5))*512 + (s&15)*32 + ((c>>3)&3)*8 + (c&7)
__global__ __launch_bounds__(512) void xpose_stats(
    const float* __restrict__ x, unsigned short* __restrict__ xT,
    float* __restrict__ p1s, float* __restrict__ p1q) {
  __shared__ float lt[64 * XP_P];  // 33792 B; 4 blocks/CU = 32 waves/CU
  int sb = blockIdx.x, cc = blockIdx.y, n = blockIdx.z;
  int t = threadIdx.x;
  int s0 = sb * 112, c0 = cc * 64;
  const float* xp = x + ((size_t)n * CC + c0) * SS + s0;
  #pragma unroll
  for (int j = 0; j < 4; j++) {
    int idx = t + 512 * j;
    if (idx < 1792) {
      int r = idx / 28, q = idx % 28;
      float4 v = *(const float4*)(xp + (size_t)r * SS + 4 * q);
      *(float4*)&lt[r * XP_P + 4 * (q ^ (r >> 3))] = v;
    }
  }
  __syncthreads();
  if (t < 256) { // per-c partial stats over this block's 112 s (exact fp32)
    int r = t >> 2, m = t & 3;
    float s = 0.f, sq = 0.f;
    #pragma unroll
    for (int i = 0; i < 7; i++) {
      int b = m * 7 + i;
      float4 v = *(const float4*)&lt[r * XP_P + 4 * (b ^ (r >> 3))];
      s  += v.x + v.y + v.z + v.w;
      sq += v.x * v.x + v.y * v.y + v.z * v.z + v.w * v.w;
    }
    s += __shfl_xor(s, 1); sq += __shfl_xor(sq, 1);
    s += __shfl_xor(s, 2); sq += __shfl_xor(sq, 2);
    if (m == 0) {
      int col = n * 14 + sb;
      p1s[(size_t)(c0 + r) * NCOL + col] = s;
      p1q[(size_t)(c0 + r) * NCOL + col] = sq;
    }
  }
  // transpose write: fragment-major
  if (t < 448) {
    int co = t & 7, sl = t >> 3;   // sl 0..55
    #pragma unroll
    for (int j = 0; j < 2; j++) {
      int sloc = sl + 56 * j;
      int s = s0 + sloc;
      bf16x8 pk;
      #pragma unroll
      for (int i = 0; i < 8; i++) {
        int r = co * 8 + i;
        pk[i] = (short)f2bf(lt[r * XP_P + 4 * ((sloc >> 2) ^ co) + (sloc & 3)]);
      }
      size_t off = (size_t)n * 1605632 +
                   (size_t)((s >> 4) * 32 + (cc * 2 + (co >> 2))) * 512 +
                   (s & 15) * 32 + (co & 3) * 8;
      *(bf16x8*)(xT + off) = pk;
    }
  }
}

// ---- merged: blocks 0..127 = bn2+nh-write; blocks 128..159 = bn1 finalize ----
__global__ void prep_stats(const float* __restrict__ nodes, const float* __restrict__ g2,
                           const float* __restrict__ b2, unsigned short* __restrict__ nh,
                           const float* __restrict__ p1s, const float* __restrict__ p1q,
                           const float* __restrict__ g1, const float* __restrict__ b1,
                           float* a1, float* c1) {
  __shared__ float sred[4][8][2];
  __shared__ float bc[8][2];
  __shared__ float red1[4][32][2];
  int t = threadIdx.x, w = t >> 6;
  if (blockIdx.x < 128) {
    int blk = blockIdx.x;
    int cl = t & 7, kq = t >> 3;
    int c = blk * 8 + cl;
    float s = 0.f, sq = 0.f;
    #pragma unroll
    for (int i = 0; i < 4; i++) {
      float v = nodes[(size_t)(kq + 32 * i) * CC + c];
      s += v; sq += v * v;
    }
    s += __shfl_xor(s, 8);  sq += __shfl_xor(sq, 8);
    s += __shfl_xor(s, 16); sq += __shfl_xor(sq, 16);
    s += __shfl_xor(s, 32); sq += __shfl_xor(sq, 32);
    if ((t & 63) < 8) { sred[w][cl][0] = s; sred[w][cl][1] = sq; }
    __syncthreads();
    if (t < 8) {
      float st = sred[0][t][0] + sred[1][t][0] + sred[2][t][0] + sred[3][t][0];
      float qt = sred[0][t][1] + sred[1][t][1] + sred[2][t][1] + sred[3][t][1];
      float inv = 1.f / (float)KK;
      float m = st * inv, var = qt * inv - m * m;
      float r = rsqrtf(var + EPSV);
      float a = g2[blk * 8 + t] * r;
      bc[t][0] = a; bc[t][1] = b2[blk * 8 + t] - m * a;
    }
    __syncthreads();
    float a = bc[cl][0], cc2 = bc[cl][1];
    #pragma unroll
    for (int i = 0; i < 4; i++) {
      int k = kq + 32 * i;
      nh[(size_t)k * CC + c] = f2bf(nodes[(size_t)k * CC + c] * a + cc2);
    }
  } else {
    int blk = blockIdx.x - 128;
    int cl = t & 31, part = t >> 5;
    int c = blk * 32 + cl;
    const float4* ps = (const float4*)(p1s + (size_t)c * NCOL + part * 56);
    const float4* pq = (const float4*)(p1q + (size_t)c * NCOL + part * 56);
    float s = 0.f, sq = 0.f;
    #pragma unroll
    for (int i = 0; i < 14; i++) {
      float4 v = ps[i]; s += v.x + v.y + v.z + v.w;
      float4 u = pq[i]; sq += u.x + u.y + u.z + u.w;
    }
    s += __shfl_xor(s, 32); sq += __shfl_xor(sq, 32);
    if ((t & 63) < 32) { red1[w][cl][0] = s; red1[w][cl][1] = sq; }
    __syncthreads();
    if (t < 32) {
      float st = red1[0][t][0] + red1[1][t][0] + red1[2][t][0] + red1[3][t][0];
      float qt = red1[0][t][1] + red1[1][t][1] + red1[2][t][1] + red1[3][t][1];
      float inv = 1.f / ((float)NB * SS);
      float m = st * inv, var = qt * inv - m * m;
      float r = rsqrtf(var + EPSV);
      float a = g1[c] * r;
      a1[c] = a; c1[c] = b1[c] - m * a;
    }
  }
}

// ---- linear via MFMA (inline W cvt): grid (32 jt, 2 mt) ----
__global__ __launch_bounds__(256) void linear_mfma(
    const unsigned short* __restrict__ nh, const float* __restrict__ Wm,
    const float* __restrict__ bW, float* __restrict__ Lb) {
  int jt = blockIdx.x, mt = blockIdx.y;
  int t = threadIdx.x, w = t >> 6, lane = t & 63, g = lane >> 4, l15 = lane & 15;
  int krow = mt * 64 + w * 16 + l15;
  f32x4 acc[2];
  acc[0] = (f32x4){0.f,0.f,0.f,0.f}; acc[1] = (f32x4){0.f,0.f,0.f,0.f};
  #pragma unroll 4
  for (int c0 = 0; c0 < CC; c0 += 32) {
    bf16x8 af = *(const bf16x8*)(nh + (size_t)krow * CC + c0 + g * 8);
    #pragma unroll
    for (int nf = 0; nf < 2; nf++) {
      const float* wr = Wm + (size_t)(jt * 32 + nf * 16 + l15) * CC + c0 + g * 8;
      float4 v0 = *(const float4*)wr, v1 = *(const float4*)(wr + 4);
      bf16x8 bfr;
      bfr[0] = (short)f2bf(v0.x); bfr[1] = (short)f2bf(v0.y);
      bfr[2] = (short)f2bf(v0.z); bfr[3] = (short)f2bf(v0.w);
      bfr[4] = (short)f2bf(v1.x); bfr[5] = (short)f2bf(v1.y);
      bfr[6] = (short)f2bf(v1.z); bfr[7] = (short)f2bf(v1.w);
      acc[nf] = __builtin_amdgcn_mfma_f32_16x16x32_bf16(af, bfr, acc[nf], 0, 0, 0);
    }
  }
  #pragma unroll
  for (int nf = 0; nf < 2; nf++) {
    int j = jt * 32 + nf * 16 + l15;
    float bwv = bW[j];
    #pragma unroll
    for (int r = 0; r < 4; r++)
      Lb[(size_t)(mt * 64 + w * 16 + g * 4 + r) * CC + j] = acc[nf][r] + bwv;
  }
}

// ---- bn3 + pack frag-major ndA2_sw, Mt_sw, plain Mt_lin, Cst ----
__global__ void bn3_pack(const float* __restrict__ Lb, const float* __restrict__ g3,
                         const float* __restrict__ b3, const float* __restrict__ loc,
                         const float* __restrict__ a1, const float* __restrict__ c1,
                         unsigned short* __restrict__ ndA2, unsigned short* __restrict__ Mt,
                         unsigned short* __restrict__ MtL, float* __restrict__ Cst) {
  __shared__ float red[8];
  int k = blockIdx.x, t = threadIdx.x, w = t >> 6;
  float vv[4];
  float s = 0.f, sq = 0.f;
  for (int i = 0; i < 4; i++) {
    float v = Lb[(size_t)k * CC + t + 256 * i];
    vv[i] = v; s += v; sq += v * v;
  }
  for (int m = 1; m < 64; m <<= 1) { s += __shfl_xor(s, m); sq += __shfl_xor(sq, m); }
  if ((t & 63) == 0) { red[w] = s; red[4 + w] = sq; }
  __syncthreads();
  s  = red[0] + red[1] + red[2] + red[3];
  sq = red[4] + red[5] + red[6] + red[7];
  float inv = 1.f / (float)CC;
  float m3 = s * inv, var = sq * inv - m3 * m3;
  float r = rsqrtf(var + EPSV);
  float a = g3[k] * r, cc3 = b3[k] - m3 * a;
  float lv = loc[0];
  float gate = 1.f / (1.f + __expf(-lv)) * 1.2f - 0.1f;
  gate = fminf(fmaxf(gate, 0.f), 1.f);
  float cs = 0.f;
  for (int i = 0; i < 4; i++) {
    int j = t + 256 * i;
    float nd = vv[i] * a + cc3;
    unsigned short ndb = f2bf(nd * a1[j]);
    unsigned short mtb = f2bf(gate * nd);
    ndA2[(size_t)((k >> 4) * 32 + (j >> 5)) * 512 + (k & 15) * 32 + ((j >> 3) & 3) * 8 + (j & 7)] = ndb;
    Mt[(size_t)((j >> 4) * 4 + (k >> 5)) * 512 + (j & 15) * 32 + ((k >> 3) & 3) * 8 + (k & 7)] = mtb;
    MtL[(size_t)j * KK + k] = mtb;
    cs += c1[j] * nd;
  }
  for (int m = 1; m < 64; m <<= 1) cs += __shfl_xor(cs, m);
  __syncthreads();
  if ((t & 63) == 0) red[w] = cs;
  __syncthreads();
  if (t == 0) Cst[k] = red[0] + red[1] + red[2] + red[3];
}

// ---- GEMM1: frag-major streaming; G[n][s][k] -> GT_sw frag-major ----
__global__ __launch_bounds__(256) void gemm1(
    const unsigned short* __restrict__ ndA2, const unsigned short* __restrict__ xT,
    const float* __restrict__ Cst, unsigned short* __restrict__ GT) {
  int sb = blockIdx.x;               // 49 (s-tiles of 32)
  int n  = blockIdx.y;
  int t = threadIdx.x, w = t >> 6, lane = t & 63, g = lane >> 4, l15 = lane & 15;
  f32x4 acc[2][2];
  for (int m = 0; m < 2; m++)
    for (int nf = 0; nf < 2; nf++) acc[m][nf] = (f32x4){0.f, 0.f, 0.f, 0.f};
  int lofs = l15 * 32 + g * 8;
  const unsigned short* xb = xT + (size_t)n * 1605632;
  #pragma unroll 4
  for (int cc2 = 0; cc2 < 32; cc2++) {
    bf16x8 af[2], bfr[2];
    #pragma unroll
    for (int m = 0; m < 2; m++)
      af[m] = *(const bf16x8*)(ndA2 + (size_t)((w * 2 + m) * 32 + cc2) * 512 + lofs);
    #pragma unroll
    for (int nf = 0; nf < 2; nf++)
      bfr[nf] = *(const bf16x8*)(xb + (size_t)((sb * 2 + nf) * 32 + cc2) * 512 + lofs);
    #pragma unroll
    for (int m = 0; m < 2; m++)
      #pragma unroll
      for (int nf = 0; nf < 2; nf++)
        acc[m][nf] = __builtin_amdgcn_mfma_f32_16x16x32_bf16(af[m], bfr[nf], acc[m][nf], 0, 0, 0);
  }
  unsigned short* gtn = GT + (size_t)n * 200704;
  #pragma unroll
  for (int nf = 0; nf < 2; nf++) {
    #pragma unroll
    for (int m = 0; m < 2; m++) {
      int kb = w * 32 + m * 16 + g * 4;
      float4 cst = *(const float4*)(Cst + kb);
      bf16x4v ov;
      ov[0] = (short)f2bf(acc[m][nf][0] + cst.x);
      ov[1] = (short)f2bf(acc[m][nf][1] + cst.y);
      ov[2] = (short)f2bf(acc[m][nf][2] + cst.z);
      ov[3] = (short)f2bf(acc[m][nf][3] + cst.w);
      int g2 = m * 2 + (g >> 1);
      int e0 = (g & 1) * 4;
      *(bf16x4v*)(gtn + (size_t)((sb * 2 + nf) * 4 + w) * 512 + l15 * 32 + g2 * 8 + e0) = ov;
    }
  }
}

// ---- Gram of G: fp32 LDS (convert once). part[b][k1*128+k2], part[b][16384+k]=rowsum ----
__global__ __launch_bounds__(256) void gram(const unsigned short* __restrict__ GT,
                                            float* __restrict__ part) {
  __shared__ float lf[112 * 128];   // 57344 B
  int b = blockIdx.x, t = threadIdx.x;
  int k1b = t >> 4, k2b = t & 15;
  float acc[8][8];
  float gsum[8];
  #pragma unroll
  for (int i = 0; i < 8; i++) {
    gsum[i] = 0.f;
    #pragma unroll
    for (int j = 0; j < 8; j++) acc[i][j] = 0.f;
  }
  for (int chunk = 0; chunk < 2; chunk++) {
    int St0 = b * 14 + chunk * 7;
    #pragma unroll
    for (int it = 0; it < 7; it++) {
      int u = t + 256 * it;              // 1792 16B-units
      int Stl = u >> 8, rem = u & 255;
      bf16x8 v = *(const bf16x8*)(GT + (size_t)(St0 + Stl) * 2048 + rem * 8);
      int sl = Stl * 16 + ((rem & 63) >> 2);
      int kk = (rem >> 6) * 32 + (rem & 3) * 8;
      float4 f0, f1;
      f0.x = bf2f((unsigned short)v[0]); f0.y = bf2f((unsigned short)v[1]);
      f0.z = bf2f((unsigned short)v[2]); f0.w = bf2f((unsigned short)v[3]);
      f1.x = bf2f((unsigned short)v[4]); f1.y = bf2f((unsigned short)v[5]);
      f1.z = bf2f((unsigned short)v[6]); f1.w = bf2f((unsigned short)v[7]);
      *(float4*)&lf[sl * 128 + kk] = f0;
      *(float4*)&lf[sl * 128 + kk + 4] = f1;
    }
    __syncthreads();
    for (int sl = 0; sl < 112; sl++) {
      float4 a0 = *(const float4*)&lf[sl * 128 + k1b * 8];
      float4 a1 = *(const float4*)&lf[sl * 128 + k1b * 8 + 4];
      float4 b0 = *(const float4*)&lf[sl * 128 + k2b * 8];
      float4 b1 = *(const float4*)&lf[sl * 128 + k2b * 8 + 4];
      float a[8]  = {a0.x, a0.y, a0.z, a0.w, a1.x, a1.y, a1.z, a1.w};
      float bb[8] = {b0.x, b0.y, b0.z, b0.w, b1.x, b1.y, b1.z, b1.w};
      #pragma unroll
      for (int i = 0; i < 8; i++)
        #pragma unroll
        for (int j = 0; j < 8; j++) acc[i][j] += a[i] * bb[j];
      if (k1b == 0) {
        #pragma unroll
        for (int j = 0; j < 8; j++) gsum[j] += bb[j];
      }
    }
    __syncthreads();
  }
  float* pb = part + (size_t)b * 16512;
  #pragma unroll
  for (int i = 0; i < 8; i++) {
    int k1 = k1b * 8 + i;
    *(float4*)(pb + k1 * 128 + k2b * 8)     = (float4){acc[i][0], acc[i][1], acc[i][2], acc[i][3]};
    *(float4*)(pb + k1 * 128 + k2b * 8 + 4) = (float4){acc[i][4], acc[i][5], acc[i][6], acc[i][7]};
  }
  if (k1b == 0) {
    *(float4*)(pb + 16384 + k2b * 8)     = (float4){gsum[0], gsum[1], gsum[2], gsum[3]};
    *(float4*)(pb + 16384 + k2b * 8 + 4) = (float4){gsum[4], gsum[5], gsum[6], gsum[7]};
  }
}

// ---- reduce 224 gram partials -> 4 partials ----
__global__ void gram_reduceA(const float* __restrict__ part, float* __restrict__ partB) {
  int e = blockIdx.x * 256 + threadIdx.x;
  if (e >= 16512) return;
  int p0 = blockIdx.y * 56;
  float s = 0.f;
  #pragma unroll 8
  for (int p = p0; p < p0 + 56; p++) s += part[(size_t)p * 16512 + e];
  partB[(size_t)blockIdx.y * 16512 + e] = s;
}

// ---- bn6 stats from 4 partB: a6[c], c6[c]. grid 128 x 256 (8 c per block) ----
__global__ __launch_bounds__(256) void bn6stats(
    const float* __restrict__ partB, const unsigned short* __restrict__ MtL,
    const float* __restrict__ g6, const float* __restrict__ b6,
    float* a6, float* c6) {
  __shared__ float covL[16384];   // 64 KB
  __shared__ float mL[8 * 128];
  __shared__ float gbL[128];
  int b = blockIdx.x, t = threadIdx.x;
  int c0 = b * 8;
  #pragma unroll
  for (int i = 0; i < 16; i++) {
    int u = (t + 256 * i) * 4;
    float4 va = *(const float4*)(partB + u);
    float4 vb = *(const float4*)(partB + 16512 + u);
    float4 vc = *(const float4*)(partB + 2 * 16512 + u);
    float4 vd = *(const float4*)(partB + 3 * 16512 + u);
    *(float4*)&covL[u] = (float4){va.x + vb.x + vc.x + vd.x, va.y + vb.y + vc.y + vd.y,
                                  va.z + vb.z + vc.z + vd.z, va.w + vb.w + vc.w + vd.w};
  }
  if (t < 128) {
    int row = t >> 4, unit = t & 15;
    bf16x8 v = *(const bf16x8*)(MtL + (size_t)(c0 + row) * KK + unit * 8);
    #pragma unroll
    for (int j = 0; j < 8; j++) mL[row * 128 + unit * 8 + j] = bf2f((unsigned short)v[j]);
  }
  if (t < 32) {
    int u = 16384 + t * 4;
    float4 va = *(const float4*)(partB + u);
    float4 vb = *(const float4*)(partB + 16512 + u);
    float4 vc = *(const float4*)(partB + 2 * 16512 + u);
    float4 vd = *(const float4*)(partB + 3 * 16512 + u);
    *(float4*)&gbL[t * 4] = (float4){va.x + vb.x + vc.x + vd.x, va.y + vb.y + vc.y + vd.y,
                                     va.z + vb.z + vc.z + vd.z, va.w + vb.w + vc.w + vd.w};
  }
  __syncthreads();
  int cl = t >> 5, kq = t & 31;
  float4 m4 = *(const float4*)&mL[cl * 128 + kq * 4];
  float4 g4 = *(const float4*)&gbL[kq * 4];
  float mv = m4.x * g4.x + m4.y * g4.y + m4.z * g4.z + m4.w * g4.w;
  float vv = 0.f;
  for (int k = 0; k < 128; k++) {
    float4 c4 = *(const float4*)&covL[k * 128 + kq * 4];
    float mk = mL[cl * 128 + k];
    vv += mk * (c4.x * m4.x + c4.y * m4.y + c4.z * m4.z + c4.w * m4.w);
  }
  for (int msk = 1; msk < 32; msk <<= 1) { mv += __shfl_xor(mv, msk); vv += __shfl_xor(vv, msk); }
  if (kq == 0) {
    int c = c0 + cl;
    float inv = 1.f / ((float)NB * SS);
    float mean = mv * inv, var = vv * inv - mean * mean;
    float r = rsqrtf(var + EPSV);
    float a = g6[c] * r;
    a6[c] = a; c6[c] = b6[c] - mean * a;
  }
}

// ---- GEMM2: XCD-swizzled; swapped-operand MFMA -> C[s][c]; f32x4 NT stores ----
__global__ __launch_bounds__(256) void gemm2(
    const unsigned short* __restrict__ Mt, const unsigned short* __restrict__ GT,
    const float* __restrict__ a6, const float* __restrict__ c6,
    float* __restrict__ out) {
  // decode: all 8 ct-blocks of a (sb,n) pair share id%8 -> same XCD -> GT tile fetched once
  int id = blockIdx.x;
  int xcd = id & 7;
  int mid = id >> 3;          // 0..447
  int ct  = mid & 7;
  int p   = (mid >> 3) * 8 + xcd;   // pair 0..447
  int sb  = p % 14, n = p / 14;
  int t = threadIdx.x, w = t >> 6, lane = t & 63, g = lane >> 4, l15 = lane & 15;
  f32x4 acc[7][2];
  for (int nf = 0; nf < 7; nf++)
    for (int m = 0; m < 2; m++) acc[nf][m] = (f32x4){0.f, 0.f, 0.f, 0.f};
  int lofs = l15 * 32 + g * 8;
  const unsigned short* gtb = GT + (size_t)n * 200704;
  #pragma unroll
  for (int ks = 0; ks < 4; ks++) {
    bf16x8 af[2];
    #pragma unroll
    for (int m = 0; m < 2; m++)
      af[m] = *(const bf16x8*)(Mt + (size_t)((ct * 8 + w * 2 + m) * 4 + ks) * 512 + lofs);
    #pragma unroll
    for (int nf = 0; nf < 7; nf++) {
      bf16x8 bfr = *(const bf16x8*)(gtb + (size_t)((sb * 7 + nf) * 4 + ks) * 512 + lofs);
      #pragma unroll
      for (int m = 0; m < 2; m++)
        acc[nf][m] = __builtin_amdgcn_mfma_f32_16x16x32_bf16(bfr, af[m], acc[nf][m], 0, 0, 0);
    }
  }
  // epilogue: C[i=s][j=c]; thread's 4 regs = 4 consecutive s in one c-row -> f32x4 NT store
  float a_[2], cc_[2];
  size_t rowbase[2];
  #pragma unroll
  for (int m = 0; m < 2; m++) {
    int c = ct * 128 + w * 32 + m * 16 + l15;
    a_[m] = a6[c]; cc_[m] = c6[c];
    rowbase[m] = ((size_t)(n * CC + c)) * SS;
  }
  #pragma unroll
  for (int nf = 0; nf < 7; nf++) {
    int s4 = sb * 112 + nf * 16 + g * 4;
    #pragma unroll
    for (int m = 0; m < 2; m++) {
      f32x4 ov;
      float v0 = acc[nf][m][0] * a_[m] + cc_[m];
      float v1 = acc[nf][m][1] * a_[m] + cc_[m];
      float v2 = acc[nf][m][2] * a_[m] + cc_[m];
      float v3 = acc[nf][m][3] * a_[m] + cc_[m];
      ov[0] = v0 >= 0.f ? v0 : 0.2f * v0;
      ov[1] = v1 >= 0.f ? v1 : 0.2f * v1;
      ov[2] = v2 >= 0.f ? v2 : 0.2f * v2;
      ov[3] = v3 >= 0.f ? v3 : 0.2f * v3;
      __builtin_nontemporal_store(ov, (f32x4*)&out[rowbase[m] + s4]);
    }
  }
}

extern "C" void kernel_launch(void* const* d_in, const int* in_sizes, int n_in,
                              void* d_out, int out_size, void* d_ws, size_t ws_size,
                              hipStream_t stream) {
  const float* x     = (const float*)d_in[0];
  const float* nodes = (const float*)d_in[1];
  const float* g1 = (const float*)d_in[2];
  const float* b1 = (const float*)d_in[3];
  const float* g2 = (const float*)d_in[4];
  const float* b2 = (const float*)d_in[5];
  const float* g3 = (const float*)d_in[6];
  const float* b3 = (const float*)d_in[7];
  const float* Wm = (const float*)d_in[8];
  const float* bW = (const float*)d_in[9];
  const float* loc = (const float*)d_in[10];
  const float* g6 = (const float*)d_in[11];
  const float* b6 = (const float*)d_in[12];
  float* out = (float*)d_out;
  char* ws = (char*)d_ws;

  float* p1s = (float*)(ws + 0);                           // 1,835,008
  float* p1q = (float*)(ws + 1835008);                     // 1,835,008
  float* a1  = (float*)(ws + 3670016);
  float* c1  = (float*)(ws + 3674112);
  float* Cst = (float*)(ws + 3678208);                     // 512 (pad 4096)
  unsigned short* nh   = (unsigned short*)(ws + 3682304);  // 262,144
  float* Lb  = (float*)(ws + 3944448);                     // 524,288
  unsigned short* ndA2 = (unsigned short*)(ws + 4468736);  // 262,144
  unsigned short* Mt   = (unsigned short*)(ws + 4730880);  // 262,144
  unsigned short* MtL  = (unsigned short*)(ws + 4993024);  // 262,144
  float* a6  = (float*)(ws + 5255168);
  float* c6  = (float*)(ws + 5259264);
  float* gramP = (float*)(ws + 5329920);                   // 14,794,752
  unsigned short* GT = (unsigned short*)(ws + 20124672);   // 12,845,056
  unsigned short* xT = (unsigned short*)(ws + 32969728);   // 102,760,448
  float* partB = (float*)(ws + 135730176);                 // 264,192 -> end ~136 MB

  xpose_stats<<<dim3(14, 16, NB), dim3(512), 0, stream>>>(x, xT, p1s, p1q);
  prep_stats<<<dim3(160), dim3(256), 0, stream>>>(nodes, g2, b2, nh, p1s, p1q, g1, b1, a1, c1);
  linear_mfma<<<dim3(32, 2), dim3(256), 0, stream>>>(nh, Wm, bW, Lb);
  bn3_pack<<<dim3(KK), dim3(256), 0, stream>>>(Lb, g3, b3, loc, a1, c1, ndA2, Mt, MtL, Cst);
  gemm1<<<dim3(49, NB), dim3(256), 0, stream>>>(ndA2, xT, Cst, GT);
  gram<<<dim3(NSB3), dim3(256), 0, stream>>>(GT, gramP);
  gram_reduceA<<<dim3(65, 4), dim3(256), 0, stream>>>(gramP, partB);
  bn6stats<<<dim3(128), dim3(256), 0, stream>>>(partB, MtL, g6, b6, a6, c6);
  gemm2<<<dim3(3584), dim3(256), 0, stream>>>(Mt, GT, a6, c6, out);
}

// Round 11
// 273.599 us; speedup vs baseline: 1.0459x; 1.0407x over previous
//
#include <hip/hip_runtime.h>
#include <hip/hip_bf16.h>

// Problem dims (fixed by setup_inputs)
#define NB 32
#define CC 1024
#define SS 1568            // T*H*W = 32*7*7
#define KK 128
#define NCOL 448           // 32 n * 14 s-blocks of 112
#define EPSV 1e-5f
#define XP_P 132           // LDS transpose pitch (floats)
#define NSB3 448           // gram blocks (112 s-rows each; 448*112 = 50176)

typedef __attribute__((ext_vector_type(8))) short bf16x8;
typedef __attribute__((ext_vector_type(4))) short bf16x4v;
typedef __attribute__((ext_vector_type(4))) float f32x4;

__device__ __forceinline__ unsigned short f2bf(float f) {
  union { float f; unsigned u; } v; v.f = f;
  return (unsigned short)((v.u + 0x7fffu + ((v.u >> 16) & 1u)) >> 16);
}
__device__ __forceinline__ float bf2f(unsigned short h) {
  union { unsigned u; float f; } v; v.u = ((unsigned)h) << 16; return v.f;
}

// ---- fused bn1 partial stats + x transpose to xT_sw (fragment-major bf16) ----
// grid (14 sb, 16 cc, 32 n), 512 threads. (r7-proven version)
// xT_sw elem (n,s,c) at:
//   n*1605632 + ((s>>4)*32 + (c>>5))*512 + (s&15)*32 + ((c>>3)&3)*8 + (c&7)
__global__ __launch_bounds__(512) void xpose_stats(
    const float* __restrict__ x, unsigned short* __restrict__ xT,
    float* __restrict__ p1s, float* __restrict__ p1q) {
  __shared__ float lt[64 * XP_P];  // 33792 B; 4 blocks/CU = 32 waves/CU
  int sb = blockIdx.x, cc = blockIdx.y, n = blockIdx.z;
  int t = threadIdx.x;
  int s0 = sb * 112, c0 = cc * 64;
  const float* xp = x + ((size_t)n * CC + c0) * SS + s0;
  #pragma unroll
  for (int j = 0; j < 4; j++) {
    int idx = t + 512 * j;
    if (idx < 1792) {
      int r = idx / 28, q = idx % 28;
      float4 v = *(const float4*)(xp + (size_t)r * SS + 4 * q);
      *(float4*)&lt[r * XP_P + 4 * (q ^ (r >> 3))] = v;
    }
  }
  __syncthreads();
  if (t < 256) { // per-c partial stats over this block's 112 s (exact fp32)
    int r = t >> 2, m = t & 3;
    float s = 0.f, sq = 0.f;
    #pragma unroll
    for (int i = 0; i < 7; i++) {
      int b = m * 7 + i;
      float4 v = *(const float4*)&lt[r * XP_P + 4 * (b ^ (r >> 3))];
      s  += v.x + v.y + v.z + v.w;
      sq += v.x * v.x + v.y * v.y + v.z * v.z + v.w * v.w;
    }
    s += __shfl_xor(s, 1); sq += __shfl_xor(sq, 1);
    s += __shfl_xor(s, 2); sq += __shfl_xor(sq, 2);
    if (m == 0) {
      int col = n * 14 + sb;
      p1s[(size_t)(c0 + r) * NCOL + col] = s;
      p1q[(size_t)(c0 + r) * NCOL + col] = sq;
    }
  }
  // transpose write: fragment-major
  if (t < 448) {
    int co = t & 7, sl = t >> 3;   // sl 0..55
    #pragma unroll
    for (int j = 0; j < 2; j++) {
      int sloc = sl + 56 * j;
      int s = s0 + sloc;
      bf16x8 pk;
      #pragma unroll
      for (int i = 0; i < 8; i++) {
        int r = co * 8 + i;
        pk[i] = (short)f2bf(lt[r * XP_P + 4 * ((sloc >> 2) ^ co) + (sloc & 3)]);
      }
      size_t off = (size_t)n * 1605632 +
                   (size_t)((s >> 4) * 32 + (cc * 2 + (co >> 2))) * 512 +
                   (s & 15) * 32 + (co & 3) * 8;
      *(bf16x8*)(xT + off) = pk;
    }
  }
}

// ---- merged: blocks 0..127 = bn2+nh-write; blocks 128..159 = bn1 finalize ----
__global__ void prep_stats(const float* __restrict__ nodes, const float* __restrict__ g2,
                           const float* __restrict__ b2, unsigned short* __restrict__ nh,
                           const float* __restrict__ p1s, const float* __restrict__ p1q,
                           const float* __restrict__ g1, const float* __restrict__ b1,
                           float* a1, float* c1) {
  __shared__ float sred[4][8][2];
  __shared__ float bc[8][2];
  __shared__ float red1[4][32][2];
  int t = threadIdx.x, w = t >> 6;
  if (blockIdx.x < 128) {
    int blk = blockIdx.x;
    int cl = t & 7, kq = t >> 3;
    int c = blk * 8 + cl;
    float s = 0.f, sq = 0.f;
    #pragma unroll
    for (int i = 0; i < 4; i++) {
      float v = nodes[(size_t)(kq + 32 * i) * CC + c];
      s += v; sq += v * v;
    }
    s += __shfl_xor(s, 8);  sq += __shfl_xor(sq, 8);
    s += __shfl_xor(s, 16); sq += __shfl_xor(sq, 16);
    s += __shfl_xor(s, 32); sq += __shfl_xor(sq, 32);
    if ((t & 63) < 8) { sred[w][cl][0] = s; sred[w][cl][1] = sq; }
    __syncthreads();
    if (t < 8) {
      float st = sred[0][t][0] + sred[1][t][0] + sred[2][t][0] + sred[3][t][0];
      float qt = sred[0][t][1] + sred[1][t][1] + sred[2][t][1] + sred[3][t][1];
      float inv = 1.f / (float)KK;
      float m = st * inv, var = qt * inv - m * m;
      float r = rsqrtf(var + EPSV);
      float a = g2[blk * 8 + t] * r;
      bc[t][0] = a; bc[t][1] = b2[blk * 8 + t] - m * a;
    }
    __syncthreads();
    float a = bc[cl][0], cc2 = bc[cl][1];
    #pragma unroll
    for (int i = 0; i < 4; i++) {
      int k = kq + 32 * i;
      nh[(size_t)k * CC + c] = f2bf(nodes[(size_t)k * CC + c] * a + cc2);
    }
  } else {
    int blk = blockIdx.x - 128;
    int cl = t & 31, part = t >> 5;
    int c = blk * 32 + cl;
    const float4* ps = (const float4*)(p1s + (size_t)c * NCOL + part * 56);
    const float4* pq = (const float4*)(p1q + (size_t)c * NCOL + part * 56);
    float s = 0.f, sq = 0.f;
    #pragma unroll
    for (int i = 0; i < 14; i++) {
      float4 v = ps[i]; s += v.x + v.y + v.z + v.w;
      float4 u = pq[i]; sq += u.x + u.y + u.z + u.w;
    }
    s += __shfl_xor(s, 32); sq += __shfl_xor(sq, 32);
    if ((t & 63) < 32) { red1[w][cl][0] = s; red1[w][cl][1] = sq; }
    __syncthreads();
    if (t < 32) {
      float st = red1[0][t][0] + red1[1][t][0] + red1[2][t][0] + red1[3][t][0];
      float qt = red1[0][t][1] + red1[1][t][1] + red1[2][t][1] + red1[3][t][1];
      float inv = 1.f / ((float)NB * SS);
      float m = st * inv, var = qt * inv - m * m;
      float r = rsqrtf(var + EPSV);
      float a = g1[c] * r;
      a1[c] = a; c1[c] = b1[c] - m * a;
    }
  }
}

// ---- linear via MFMA (inline W cvt): grid (32 jt, 2 mt) ----
__global__ __launch_bounds__(256) void linear_mfma(
    const unsigned short* __restrict__ nh, const float* __restrict__ Wm,
    const float* __restrict__ bW, float* __restrict__ Lb) {
  int jt = blockIdx.x, mt = blockIdx.y;
  int t = threadIdx.x, w = t >> 6, lane = t & 63, g = lane >> 4, l15 = lane & 15;
  int krow = mt * 64 + w * 16 + l15;
  f32x4 acc[2];
  acc[0] = (f32x4){0.f,0.f,0.f,0.f}; acc[1] = (f32x4){0.f,0.f,0.f,0.f};
  #pragma unroll 4
  for (int c0 = 0; c0 < CC; c0 += 32) {
    bf16x8 af = *(const bf16x8*)(nh + (size_t)krow * CC + c0 + g * 8);
    #pragma unroll
    for (int nf = 0; nf < 2; nf++) {
      const float* wr = Wm + (size_t)(jt * 32 + nf * 16 + l15) * CC + c0 + g * 8;
      float4 v0 = *(const float4*)wr, v1 = *(const float4*)(wr + 4);
      bf16x8 bfr;
      bfr[0] = (short)f2bf(v0.x); bfr[1] = (short)f2bf(v0.y);
      bfr[2] = (short)f2bf(v0.z); bfr[3] = (short)f2bf(v0.w);
      bfr[4] = (short)f2bf(v1.x); bfr[5] = (short)f2bf(v1.y);
      bfr[6] = (short)f2bf(v1.z); bfr[7] = (short)f2bf(v1.w);
      acc[nf] = __builtin_amdgcn_mfma_f32_16x16x32_bf16(af, bfr, acc[nf], 0, 0, 0);
    }
  }
  #pragma unroll
  for (int nf = 0; nf < 2; nf++) {
    int j = jt * 32 + nf * 16 + l15;
    float bwv = bW[j];
    #pragma unroll
    for (int r = 0; r < 4; r++)
      Lb[(size_t)(mt * 64 + w * 16 + g * 4 + r) * CC + j] = acc[nf][r] + bwv;
  }
}

// ---- bn3 + pack frag-major ndA2_sw, Mt_sw, plain Mt_lin, Cst ----
__global__ void bn3_pack(const float* __restrict__ Lb, const float* __restrict__ g3,
                         const float* __restrict__ b3, const float* __restrict__ loc,
                         const float* __restrict__ a1, const float* __restrict__ c1,
                         unsigned short* __restrict__ ndA2, unsigned short* __restrict__ Mt,
                         unsigned short* __restrict__ MtL, float* __restrict__ Cst) {
  __shared__ float red[8];
  int k = blockIdx.x, t = threadIdx.x, w = t >> 6;
  float vv[4];
  float s = 0.f, sq = 0.f;
  for (int i = 0; i < 4; i++) {
    float v = Lb[(size_t)k * CC + t + 256 * i];
    vv[i] = v; s += v; sq += v * v;
  }
  for (int m = 1; m < 64; m <<= 1) { s += __shfl_xor(s, m); sq += __shfl_xor(sq, m); }
  if ((t & 63) == 0) { red[w] = s; red[4 + w] = sq; }
  __syncthreads();
  s  = red[0] + red[1] + red[2] + red[3];
  sq = red[4] + red[5] + red[6] + red[7];
  float inv = 1.f / (float)CC;
  float m3 = s * inv, var = sq * inv - m3 * m3;
  float r = rsqrtf(var + EPSV);
  float a = g3[k] * r, cc3 = b3[k] - m3 * a;
  float lv = loc[0];
  float gate = 1.f / (1.f + __expf(-lv)) * 1.2f - 0.1f;
  gate = fminf(fmaxf(gate, 0.f), 1.f);
  float cs = 0.f;
  for (int i = 0; i < 4; i++) {
    int j = t + 256 * i;
    float nd = vv[i] * a + cc3;
    unsigned short ndb = f2bf(nd * a1[j]);
    unsigned short mtb = f2bf(gate * nd);
    ndA2[(size_t)((k >> 4) * 32 + (j >> 5)) * 512 + (k & 15) * 32 + ((j >> 3) & 3) * 8 + (j & 7)] = ndb;
    Mt[(size_t)((j >> 4) * 4 + (k >> 5)) * 512 + (j & 15) * 32 + ((k >> 3) & 3) * 8 + (k & 7)] = mtb;
    MtL[(size_t)j * KK + k] = mtb;
    cs += c1[j] * nd;
  }
  for (int m = 1; m < 64; m <<= 1) cs += __shfl_xor(cs, m);
  __syncthreads();
  if ((t & 63) == 0) red[w] = cs;
  __syncthreads();
  if (t == 0) Cst[k] = red[0] + red[1] + red[2] + red[3];
}

// ---- GEMM1: frag-major streaming; G[n][s][k] -> GT_sw frag-major ----
__global__ __launch_bounds__(256) void gemm1(
    const unsigned short* __restrict__ ndA2, const unsigned short* __restrict__ xT,
    const float* __restrict__ Cst, unsigned short* __restrict__ GT) {
  int sb = blockIdx.x;               // 49 (s-tiles of 32)
  int n  = blockIdx.y;
  int t = threadIdx.x, w = t >> 6, lane = t & 63, g = lane >> 4, l15 = lane & 15;
  f32x4 acc[2][2];
  for (int m = 0; m < 2; m++)
    for (int nf = 0; nf < 2; nf++) acc[m][nf] = (f32x4){0.f, 0.f, 0.f, 0.f};
  int lofs = l15 * 32 + g * 8;
  const unsigned short* xb = xT + (size_t)n * 1605632;
  #pragma unroll 4
  for (int cc2 = 0; cc2 < 32; cc2++) {
    bf16x8 af[2], bfr[2];
    #pragma unroll
    for (int m = 0; m < 2; m++)
      af[m] = *(const bf16x8*)(ndA2 + (size_t)((w * 2 + m) * 32 + cc2) * 512 + lofs);
    #pragma unroll
    for (int nf = 0; nf < 2; nf++)
      bfr[nf] = *(const bf16x8*)(xb + (size_t)((sb * 2 + nf) * 32 + cc2) * 512 + lofs);
    #pragma unroll
    for (int m = 0; m < 2; m++)
      #pragma unroll
      for (int nf = 0; nf < 2; nf++)
        acc[m][nf] = __builtin_amdgcn_mfma_f32_16x16x32_bf16(af[m], bfr[nf], acc[m][nf], 0, 0, 0);
  }
  unsigned short* gtn = GT + (size_t)n * 200704;
  #pragma unroll
  for (int nf = 0; nf < 2; nf++) {
    #pragma unroll
    for (int m = 0; m < 2; m++) {
      int kb = w * 32 + m * 16 + g * 4;
      float4 cst = *(const float4*)(Cst + kb);
      bf16x4v ov;
      ov[0] = (short)f2bf(acc[m][nf][0] + cst.x);
      ov[1] = (short)f2bf(acc[m][nf][1] + cst.y);
      ov[2] = (short)f2bf(acc[m][nf][2] + cst.z);
      ov[3] = (short)f2bf(acc[m][nf][3] + cst.w);
      int g2 = m * 2 + (g >> 1);
      int e0 = (g & 1) * 4;
      *(bf16x4v*)(gtn + (size_t)((sb * 2 + nf) * 4 + w) * 512 + l15 * 32 + g2 * 8 + e0) = ov;
    }
  }
}

// ---- Gram of G: fp32 LDS; 448 blocks x 112 s-rows. part[b][k1*128+k2], part[b][16384+k]=rowsum ----
__global__ __launch_bounds__(256) void gram(const unsigned short* __restrict__ GT,
                                            float* __restrict__ part) {
  __shared__ float lf[112 * 128];   // 57344 B
  int b = blockIdx.x, t = threadIdx.x;
  int k1b = t >> 4, k2b = t & 15;
  float acc[8][8];
  float gsum[8];
  #pragma unroll
  for (int i = 0; i < 8; i++) {
    gsum[i] = 0.f;
    #pragma unroll
    for (int j = 0; j < 8; j++) acc[i][j] = 0.f;
  }
  int St0 = b * 7;
  #pragma unroll
  for (int it = 0; it < 7; it++) {
    int u = t + 256 * it;              // 1792 16B-units
    int Stl = u >> 8, rem = u & 255;
    bf16x8 v = *(const bf16x8*)(GT + (size_t)(St0 + Stl) * 2048 + rem * 8);
    int sl = Stl * 16 + ((rem & 63) >> 2);
    int kk = (rem >> 6) * 32 + (rem & 3) * 8;
    float4 f0, f1;
    f0.x = bf2f((unsigned short)v[0]); f0.y = bf2f((unsigned short)v[1]);
    f0.z = bf2f((unsigned short)v[2]); f0.w = bf2f((unsigned short)v[3]);
    f1.x = bf2f((unsigned short)v[4]); f1.y = bf2f((unsigned short)v[5]);
    f1.z = bf2f((unsigned short)v[6]); f1.w = bf2f((unsigned short)v[7]);
    *(float4*)&lf[sl * 128 + kk] = f0;
    *(float4*)&lf[sl * 128 + kk + 4] = f1;
  }
  __syncthreads();
  for (int sl = 0; sl < 112; sl++) {
    float4 a0 = *(const float4*)&lf[sl * 128 + k1b * 8];
    float4 a1 = *(const float4*)&lf[sl * 128 + k1b * 8 + 4];
    float4 b0 = *(const float4*)&lf[sl * 128 + k2b * 8];
    float4 b1 = *(const float4*)&lf[sl * 128 + k2b * 8 + 4];
    float a[8]  = {a0.x, a0.y, a0.z, a0.w, a1.x, a1.y, a1.z, a1.w};
    float bb[8] = {b0.x, b0.y, b0.z, b0.w, b1.x, b1.y, b1.z, b1.w};
    #pragma unroll
    for (int i = 0; i < 8; i++)
      #pragma unroll
      for (int j = 0; j < 8; j++) acc[i][j] += a[i] * bb[j];
    if (k1b == 0) {
      #pragma unroll
      for (int j = 0; j < 8; j++) gsum[j] += bb[j];
    }
  }
  float* pb = part + (size_t)b * 16512;
  #pragma unroll
  for (int i = 0; i < 8; i++) {
    int k1 = k1b * 8 + i;
    *(float4*)(pb + k1 * 128 + k2b * 8)     = (float4){acc[i][0], acc[i][1], acc[i][2], acc[i][3]};
    *(float4*)(pb + k1 * 128 + k2b * 8 + 4) = (float4){acc[i][4], acc[i][5], acc[i][6], acc[i][7]};
  }
  if (k1b == 0) {
    *(float4*)(pb + 16384 + k2b * 8)     = (float4){gsum[0], gsum[1], gsum[2], gsum[3]};
    *(float4*)(pb + 16384 + k2b * 8 + 4) = (float4){gsum[4], gsum[5], gsum[6], gsum[7]};
  }
}

// ---- reduce 448 gram partials -> 4 partials ----
__global__ void gram_reduceA(const float* __restrict__ part, float* __restrict__ partB) {
  int e = blockIdx.x * 256 + threadIdx.x;
  if (e >= 16512) return;
  int p0 = blockIdx.y * 112;
  float s = 0.f;
  #pragma unroll 8
  for (int p = p0; p < p0 + 112; p++) s += part[(size_t)p * 16512 + e];
  partB[(size_t)blockIdx.y * 16512 + e] = s;
}

// ---- bn6 stats from 4 partB: a6[c], c6[c]. grid 128 x 256 (8 c per block) ----
__global__ __launch_bounds__(256) void bn6stats(
    const float* __restrict__ partB, const unsigned short* __restrict__ MtL,
    const float* __restrict__ g6, const float* __restrict__ b6,
    float* a6, float* c6) {
  __shared__ float covL[16384];   // 64 KB
  __shared__ float mL[8 * 128];
  __shared__ float gbL[128];
  int b = blockIdx.x, t = threadIdx.x;
  int c0 = b * 8;
  #pragma unroll
  for (int i = 0; i < 16; i++) {
    int u = (t + 256 * i) * 4;
    float4 va = *(const float4*)(partB + u);
    float4 vb = *(const float4*)(partB + 16512 + u);
    float4 vc = *(const float4*)(partB + 2 * 16512 + u);
    float4 vd = *(const float4*)(partB + 3 * 16512 + u);
    *(float4*)&covL[u] = (float4){va.x + vb.x + vc.x + vd.x, va.y + vb.y + vc.y + vd.y,
                                  va.z + vb.z + vc.z + vd.z, va.w + vb.w + vc.w + vd.w};
  }
  if (t < 128) {
    int row = t >> 4, unit = t & 15;
    bf16x8 v = *(const bf16x8*)(MtL + (size_t)(c0 + row) * KK + unit * 8);
    #pragma unroll
    for (int j = 0; j < 8; j++) mL[row * 128 + unit * 8 + j] = bf2f((unsigned short)v[j]);
  }
  if (t < 32) {
    int u = 16384 + t * 4;
    float4 va = *(const float4*)(partB + u);
    float4 vb = *(const float4*)(partB + 16512 + u);
    float4 vc = *(const float4*)(partB + 2 * 16512 + u);
    float4 vd = *(const float4*)(partB + 3 * 16512 + u);
    *(float4*)&gbL[t * 4] = (float4){va.x + vb.x + vc.x + vd.x, va.y + vb.y + vc.y + vd.y,
                                     va.z + vb.z + vc.z + vd.z, va.w + vb.w + vc.w + vd.w};
  }
  __syncthreads();
  int cl = t >> 5, kq = t & 31;
  float4 m4 = *(const float4*)&mL[cl * 128 + kq * 4];
  float4 g4 = *(const float4*)&gbL[kq * 4];
  float mv = m4.x * g4.x + m4.y * g4.y + m4.z * g4.z + m4.w * g4.w;
  float vv = 0.f;
  for (int k = 0; k < 128; k++) {
    float4 c4 = *(const float4*)&covL[k * 128 + kq * 4];
    float mk = mL[cl * 128 + k];
    vv += mk * (c4.x * m4.x + c4.y * m4.y + c4.z * m4.z + c4.w * m4.w);
  }
  for (int msk = 1; msk < 32; msk <<= 1) { mv += __shfl_xor(mv, msk); vv += __shfl_xor(vv, msk); }
  if (kq == 0) {
    int c = c0 + cl;
    float inv = 1.f / ((float)NB * SS);
    float mean = mv * inv, var = vv * inv - mean * mean;
    float r = rsqrtf(var + EPSV);
    float a = g6[c] * r;
    a6[c] = a; c6[c] = b6[c] - mean * a;
  }
}

// ---- GEMM2: XCD-swizzled 1D grid (3584); fused bn6 + LeakyReLU; nt fp32 out (r7-proven) ----
__global__ __launch_bounds__(256) void gemm2(
    const unsigned short* __restrict__ Mt, const unsigned short* __restrict__ GT,
    const float* __restrict__ a6, const float* __restrict__ c6,
    float* __restrict__ out) {
  // decode: all 8 ct-blocks of a (sb,n) pair share id%8 -> same XCD -> GT tile fetched once
  int id = blockIdx.x;
  int xcd = id & 7;
  int mid = id >> 3;          // 0..447
  int ct  = mid & 7;
  int p   = (mid >> 3) * 8 + xcd;   // pair 0..447
  int sb  = p % 14, n = p / 14;
  int t = threadIdx.x, w = t >> 6, lane = t & 63, g = lane >> 4, l15 = lane & 15;
  f32x4 acc[2][7];
  for (int m = 0; m < 2; m++)
    for (int nf = 0; nf < 7; nf++) acc[m][nf] = (f32x4){0.f, 0.f, 0.f, 0.f};
  int lofs = l15 * 32 + g * 8;
  const unsigned short* gtb = GT + (size_t)n * 200704;
  #pragma unroll
  for (int ks = 0; ks < 4; ks++) {
    bf16x8 af[2];
    #pragma unroll
    for (int m = 0; m < 2; m++)
      af[m] = *(const bf16x8*)(Mt + (size_t)((ct * 8 + w * 2 + m) * 4 + ks) * 512 + lofs);
    #pragma unroll
    for (int nf = 0; nf < 7; nf++) {
      bf16x8 bfr = *(const bf16x8*)(gtb + (size_t)((sb * 7 + nf) * 4 + ks) * 512 + lofs);
      #pragma unroll
      for (int m = 0; m < 2; m++)
        acc[m][nf] = __builtin_amdgcn_mfma_f32_16x16x32_bf16(af[m], bfr, acc[m][nf], 0, 0, 0);
    }
  }
  #pragma unroll
  for (int m = 0; m < 2; m++) {
    int cb = ct * 128 + w * 32 + m * 16 + g * 4;
    float4 av = *(const float4*)(a6 + cb);
    float4 cv = *(const float4*)(c6 + cb);
    #pragma unroll
    for (int nf = 0; nf < 7; nf++) {
      int s = sb * 112 + nf * 16 + l15;
      #pragma unroll
      for (int r = 0; r < 4; r++) {
        float a = (r == 0) ? av.x : (r == 1) ? av.y : (r == 2) ? av.z : av.w;
        float cc = (r == 0) ? cv.x : (r == 1) ? cv.y : (r == 2) ? cv.z : cv.w;
        float v = acc[m][nf][r] * a + cc;
        v = v >= 0.f ? v : 0.2f * v;
        __builtin_nontemporal_store(v, &out[((size_t)(n * CC + cb + r)) * SS + s]);
      }
    }
  }
}

extern "C" void kernel_launch(void* const* d_in, const int* in_sizes, int n_in,
                              void* d_out, int out_size, void* d_ws, size_t ws_size,
                              hipStream_t stream) {
  const float* x     = (const float*)d_in[0];
  const float* nodes = (const float*)d_in[1];
  const float* g1 = (const float*)d_in[2];
  const float* b1 = (const float*)d_in[3];
  const float* g2 = (const float*)d_in[4];
  const float* b2 = (const float*)d_in[5];
  const float* g3 = (const float*)d_in[6];
  const float* b3 = (const float*)d_in[7];
  const float* Wm = (const float*)d_in[8];
  const float* bW = (const float*)d_in[9];
  const float* loc = (const float*)d_in[10];
  const float* g6 = (const float*)d_in[11];
  const float* b6 = (const float*)d_in[12];
  float* out = (float*)d_out;
  char* ws = (char*)d_ws;

  float* p1s = (float*)(ws + 0);                           // 1,835,008
  float* p1q = (float*)(ws + 1835008);                     // 1,835,008
  float* a1  = (float*)(ws + 3670016);
  float* c1  = (float*)(ws + 3674112);
  float* Cst = (float*)(ws + 3678208);                     // 512 (pad 4096)
  unsigned short* nh   = (unsigned short*)(ws + 3682304);  // 262,144
  float* Lb  = (float*)(ws + 3944448);                     // 524,288
  unsigned short* ndA2 = (unsigned short*)(ws + 4468736);  // 262,144
  unsigned short* Mt   = (unsigned short*)(ws + 4730880);  // 262,144
  unsigned short* MtL  = (unsigned short*)(ws + 4993024);  // 262,144
  float* a6  = (float*)(ws + 5255168);
  float* c6  = (float*)(ws + 5259264);
  float* gramP = (float*)(ws + 5329920);                   // 448*16512*4 = 29,589,504
  unsigned short* GT = (unsigned short*)(ws + 34919424);   // 12,845,056
  unsigned short* xT = (unsigned short*)(ws + 47764480);   // 102,760,448
  float* partB = (float*)(ws + 150524928);                 // 264,192 -> end ~150.8 MB

  xpose_stats<<<dim3(14, 16, NB), dim3(512), 0, stream>>>(x, xT, p1s, p1q);
  prep_stats<<<dim3(160), dim3(256), 0, stream>>>(nodes, g2, b2, nh, p1s, p1q, g1, b1, a1, c1);
  linear_mfma<<<dim3(32, 2), dim3(256), 0, stream>>>(nh, Wm, bW, Lb);
  bn3_pack<<<dim3(KK), dim3(256), 0, stream>>>(Lb, g3, b3, loc, a1, c1, ndA2, Mt, MtL, Cst);
  gemm1<<<dim3(49, NB), dim3(256), 0, stream>>>(ndA2, xT, Cst, GT);
  gram<<<dim3(NSB3), dim3(256), 0, stream>>>(GT, gramP);
  gram_reduceA<<<dim3(65, 4), dim3(256), 0, stream>>>(gramP, partB);
  bn6stats<<<dim3(128), dim3(256), 0, stream>>>(partB, MtL, g6, b6, a6, c6);
  gemm2<<<dim3(3584), dim3(256), 0, stream>>>(Mt, GT, a6, c6, out);
}

// Round 12
// 271.186 us; speedup vs baseline: 1.0552x; 1.0089x over previous
//
#include <hip/hip_runtime.h>
#include <hip/hip_bf16.h>

// Problem dims (fixed by setup_inputs)
#define NB 32
#define CC 1024
#define SS 1568            // T*H*W = 32*7*7
#define KK 128
#define NCOL 448           // 32 n * 14 s-blocks of 112
#define EPSV 1e-5f
#define XP_P 132           // LDS transpose pitch (floats)
#define NSB3 448           // gram blocks (112 s-rows each; 448*112 = 50176)

typedef __attribute__((ext_vector_type(8))) short bf16x8;
typedef __attribute__((ext_vector_type(4))) short bf16x4v;
typedef __attribute__((ext_vector_type(4))) float f32x4;

__device__ __forceinline__ unsigned short f2bf(float f) {
  union { float f; unsigned u; } v; v.f = f;
  return (unsigned short)((v.u + 0x7fffu + ((v.u >> 16) & 1u)) >> 16);
}
__device__ __forceinline__ float bf2f(unsigned short h) {
  union { unsigned u; float f; } v; v.u = ((unsigned)h) << 16; return v.f;
}

// ---- fused bn1 partial stats + x transpose to xT_sw (fragment-major bf16) ----
// grid (14 sb, 16 cc, 32 n), 512 threads.
// Load phase (t<448): thread owns a 64B row-chunk (7 thr/row), accumulates
// s/sq in REGISTERS during the load (cached loads, no NT), stores swizzled LDS
// + 4KB aux partials. After barrier: wave 7 (t>=448, idle in transpose)
// finalizes stats; waves 0-6 do the (r7-proven) transpose. Full overlap.
// xT_sw elem (n,s,c) at:
//   n*1605632 + ((s>>4)*32 + (c>>5))*512 + (s&15)*32 + ((c>>3)&3)*8 + (c&7)
__global__ __launch_bounds__(512) void xpose_stats(
    const float* __restrict__ x, unsigned short* __restrict__ xT,
    float* __restrict__ p1s, float* __restrict__ p1q) {
  __shared__ float lt[64 * XP_P];            // 33792 B
  __shared__ float axs[64][8], axq[64][8];   // 4 KB partial stats
  int sb = blockIdx.x, cc = blockIdx.y, n = blockIdx.z;
  int t = threadIdx.x;
  int s0 = sb * 112, c0 = cc * 64;
  const float* xp = x + ((size_t)n * CC + c0) * SS + s0;
  if (t < 448) {
    int r = t / 7, j7 = t % 7;
    int qb = j7 * 4;
    float s = 0.f, sq = 0.f;
    #pragma unroll
    for (int j = 0; j < 4; j++) {
      int q = qb + j;
      float4 v = *(const float4*)(xp + (size_t)r * SS + 4 * q);   // cached, coalesced
      *(float4*)&lt[r * XP_P + 4 * (q ^ (r >> 3))] = v;
      s  += v.x + v.y + v.z + v.w;
      sq += v.x * v.x + v.y * v.y + v.z * v.z + v.w * v.w;
    }
    axs[r][j7] = s; axq[r][j7] = sq;
  }
  __syncthreads();
  if (t >= 448) {
    // stats finalize on the transpose-idle wave: one thread per c-row
    int r = t - 448;
    float s = 0.f, sq = 0.f;
    #pragma unroll
    for (int j = 0; j < 7; j++) { s += axs[r][j]; sq += axq[r][j]; }
    int col = n * 14 + sb;
    p1s[(size_t)(c0 + r) * NCOL + col] = s;
    p1q[(size_t)(c0 + r) * NCOL + col] = sq;
  } else {
    // transpose write: fragment-major (r7-proven)
    int co = t & 7, sl = t >> 3;   // sl 0..55
    #pragma unroll
    for (int j = 0; j < 2; j++) {
      int sloc = sl + 56 * j;
      int s = s0 + sloc;
      bf16x8 pk;
      #pragma unroll
      for (int i = 0; i < 8; i++) {
        int r = co * 8 + i;
        pk[i] = (short)f2bf(lt[r * XP_P + 4 * ((sloc >> 2) ^ co) + (sloc & 3)]);
      }
      size_t off = (size_t)n * 1605632 +
                   (size_t)((s >> 4) * 32 + (cc * 2 + (co >> 2))) * 512 +
                   (s & 15) * 32 + (co & 3) * 8;
      *(bf16x8*)(xT + off) = pk;
    }
  }
}

// ---- merged: blocks 0..127 = bn2+nh-write; blocks 128..159 = bn1 finalize ----
__global__ void prep_stats(const float* __restrict__ nodes, const float* __restrict__ g2,
                           const float* __restrict__ b2, unsigned short* __restrict__ nh,
                           const float* __restrict__ p1s, const float* __restrict__ p1q,
                           const float* __restrict__ g1, const float* __restrict__ b1,
                           float* a1, float* c1) {
  __shared__ float sred[4][8][2];
  __shared__ float bc[8][2];
  __shared__ float red1[4][32][2];
  int t = threadIdx.x, w = t >> 6;
  if (blockIdx.x < 128) {
    int blk = blockIdx.x;
    int cl = t & 7, kq = t >> 3;
    int c = blk * 8 + cl;
    float s = 0.f, sq = 0.f;
    #pragma unroll
    for (int i = 0; i < 4; i++) {
      float v = nodes[(size_t)(kq + 32 * i) * CC + c];
      s += v; sq += v * v;
    }
    s += __shfl_xor(s, 8);  sq += __shfl_xor(sq, 8);
    s += __shfl_xor(s, 16); sq += __shfl_xor(sq, 16);
    s += __shfl_xor(s, 32); sq += __shfl_xor(sq, 32);
    if ((t & 63) < 8) { sred[w][cl][0] = s; sred[w][cl][1] = sq; }
    __syncthreads();
    if (t < 8) {
      float st = sred[0][t][0] + sred[1][t][0] + sred[2][t][0] + sred[3][t][0];
      float qt = sred[0][t][1] + sred[1][t][1] + sred[2][t][1] + sred[3][t][1];
      float inv = 1.f / (float)KK;
      float m = st * inv, var = qt * inv - m * m;
      float r = rsqrtf(var + EPSV);
      float a = g2[blk * 8 + t] * r;
      bc[t][0] = a; bc[t][1] = b2[blk * 8 + t] - m * a;
    }
    __syncthreads();
    float a = bc[cl][0], cc2 = bc[cl][1];
    #pragma unroll
    for (int i = 0; i < 4; i++) {
      int k = kq + 32 * i;
      nh[(size_t)k * CC + c] = f2bf(nodes[(size_t)k * CC + c] * a + cc2);
    }
  } else {
    int blk = blockIdx.x - 128;
    int cl = t & 31, part = t >> 5;
    int c = blk * 32 + cl;
    const float4* ps = (const float4*)(p1s + (size_t)c * NCOL + part * 56);
    const float4* pq = (const float4*)(p1q + (size_t)c * NCOL + part * 56);
    float s = 0.f, sq = 0.f;
    #pragma unroll
    for (int i = 0; i < 14; i++) {
      float4 v = ps[i]; s += v.x + v.y + v.z + v.w;
      float4 u = pq[i]; sq += u.x + u.y + u.z + u.w;
    }
    s += __shfl_xor(s, 32); sq += __shfl_xor(sq, 32);
    if ((t & 63) < 32) { red1[w][cl][0] = s; red1[w][cl][1] = sq; }
    __syncthreads();
    if (t < 32) {
      float st = red1[0][t][0] + red1[1][t][0] + red1[2][t][0] + red1[3][t][0];
      float qt = red1[0][t][1] + red1[1][t][1] + red1[2][t][1] + red1[3][t][1];
      float inv = 1.f / ((float)NB * SS);
      float m = st * inv, var = qt * inv - m * m;
      float r = rsqrtf(var + EPSV);
      float a = g1[c] * r;
      a1[c] = a; c1[c] = b1[c] - m * a;
    }
  }
}

// ---- linear via MFMA (inline W cvt): grid (32 jt, 2 mt) ----
__global__ __launch_bounds__(256) void linear_mfma(
    const unsigned short* __restrict__ nh, const float* __restrict__ Wm,
    const float* __restrict__ bW, float* __restrict__ Lb) {
  int jt = blockIdx.x, mt = blockIdx.y;
  int t = threadIdx.x, w = t >> 6, lane = t & 63, g = lane >> 4, l15 = lane & 15;
  int krow = mt * 64 + w * 16 + l15;
  f32x4 acc[2];
  acc[0] = (f32x4){0.f,0.f,0.f,0.f}; acc[1] = (f32x4){0.f,0.f,0.f,0.f};
  #pragma unroll 4
  for (int c0 = 0; c0 < CC; c0 += 32) {
    bf16x8 af = *(const bf16x8*)(nh + (size_t)krow * CC + c0 + g * 8);
    #pragma unroll
    for (int nf = 0; nf < 2; nf++) {
      const float* wr = Wm + (size_t)(jt * 32 + nf * 16 + l15) * CC + c0 + g * 8;
      float4 v0 = *(const float4*)wr, v1 = *(const float4*)(wr + 4);
      bf16x8 bfr;
      bfr[0] = (short)f2bf(v0.x); bfr[1] = (short)f2bf(v0.y);
      bfr[2] = (short)f2bf(v0.z); bfr[3] = (short)f2bf(v0.w);
      bfr[4] = (short)f2bf(v1.x); bfr[5] = (short)f2bf(v1.y);
      bfr[6] = (short)f2bf(v1.z); bfr[7] = (short)f2bf(v1.w);
      acc[nf] = __builtin_amdgcn_mfma_f32_16x16x32_bf16(af, bfr, acc[nf], 0, 0, 0);
    }
  }
  #pragma unroll
  for (int nf = 0; nf < 2; nf++) {
    int j = jt * 32 + nf * 16 + l15;
    float bwv = bW[j];
    #pragma unroll
    for (int r = 0; r < 4; r++)
      Lb[(size_t)(mt * 64 + w * 16 + g * 4 + r) * CC + j] = acc[nf][r] + bwv;
  }
}

// ---- bn3 + pack frag-major ndA2_sw, Mt_sw, plain Mt_lin, Cst ----
__global__ void bn3_pack(const float* __restrict__ Lb, const float* __restrict__ g3,
                         const float* __restrict__ b3, const float* __restrict__ loc,
                         const float* __restrict__ a1, const float* __restrict__ c1,
                         unsigned short* __restrict__ ndA2, unsigned short* __restrict__ Mt,
                         unsigned short* __restrict__ MtL, float* __restrict__ Cst) {
  __shared__ float red[8];
  int k = blockIdx.x, t = threadIdx.x, w = t >> 6;
  float vv[4];
  float s = 0.f, sq = 0.f;
  for (int i = 0; i < 4; i++) {
    float v = Lb[(size_t)k * CC + t + 256 * i];
    vv[i] = v; s += v; sq += v * v;
  }
  for (int m = 1; m < 64; m <<= 1) { s += __shfl_xor(s, m); sq += __shfl_xor(sq, m); }
  if ((t & 63) == 0) { red[w] = s; red[4 + w] = sq; }
  __syncthreads();
  s  = red[0] + red[1] + red[2] + red[3];
  sq = red[4] + red[5] + red[6] + red[7];
  float inv = 1.f / (float)CC;
  float m3 = s * inv, var = sq * inv - m3 * m3;
  float r = rsqrtf(var + EPSV);
  float a = g3[k] * r, cc3 = b3[k] - m3 * a;
  float lv = loc[0];
  float gate = 1.f / (1.f + __expf(-lv)) * 1.2f - 0.1f;
  gate = fminf(fmaxf(gate, 0.f), 1.f);
  float cs = 0.f;
  for (int i = 0; i < 4; i++) {
    int j = t + 256 * i;
    float nd = vv[i] * a + cc3;
    unsigned short ndb = f2bf(nd * a1[j]);
    unsigned short mtb = f2bf(gate * nd);
    ndA2[(size_t)((k >> 4) * 32 + (j >> 5)) * 512 + (k & 15) * 32 + ((j >> 3) & 3) * 8 + (j & 7)] = ndb;
    Mt[(size_t)((j >> 4) * 4 + (k >> 5)) * 512 + (j & 15) * 32 + ((k >> 3) & 3) * 8 + (k & 7)] = mtb;
    MtL[(size_t)j * KK + k] = mtb;
    cs += c1[j] * nd;
  }
  for (int m = 1; m < 64; m <<= 1) cs += __shfl_xor(cs, m);
  __syncthreads();
  if ((t & 63) == 0) red[w] = cs;
  __syncthreads();
  if (t == 0) Cst[k] = red[0] + red[1] + red[2] + red[3];
}

// ---- GEMM1: frag-major streaming; G[n][s][k] -> GT_sw frag-major ----
__global__ __launch_bounds__(256) void gemm1(
    const unsigned short* __restrict__ ndA2, const unsigned short* __restrict__ xT,
    const float* __restrict__ Cst, unsigned short* __restrict__ GT) {
  int sb = blockIdx.x;               // 49 (s-tiles of 32)
  int n  = blockIdx.y;
  int t = threadIdx.x, w = t >> 6, lane = t & 63, g = lane >> 4, l15 = lane & 15;
  f32x4 acc[2][2];
  for (int m = 0; m < 2; m++)
    for (int nf = 0; nf < 2; nf++) acc[m][nf] = (f32x4){0.f, 0.f, 0.f, 0.f};
  int lofs = l15 * 32 + g * 8;
  const unsigned short* xb = xT + (size_t)n * 1605632;
  #pragma unroll 4
  for (int cc2 = 0; cc2 < 32; cc2++) {
    bf16x8 af[2], bfr[2];
    #pragma unroll
    for (int m = 0; m < 2; m++)
      af[m] = *(const bf16x8*)(ndA2 + (size_t)((w * 2 + m) * 32 + cc2) * 512 + lofs);
    #pragma unroll
    for (int nf = 0; nf < 2; nf++)
      bfr[nf] = *(const bf16x8*)(xb + (size_t)((sb * 2 + nf) * 32 + cc2) * 512 + lofs);
    #pragma unroll
    for (int m = 0; m < 2; m++)
      #pragma unroll
      for (int nf = 0; nf < 2; nf++)
        acc[m][nf] = __builtin_amdgcn_mfma_f32_16x16x32_bf16(af[m], bfr[nf], acc[m][nf], 0, 0, 0);
  }
  unsigned short* gtn = GT + (size_t)n * 200704;
  #pragma unroll
  for (int nf = 0; nf < 2; nf++) {
    #pragma unroll
    for (int m = 0; m < 2; m++) {
      int kb = w * 32 + m * 16 + g * 4;
      float4 cst = *(const float4*)(Cst + kb);
      bf16x4v ov;
      ov[0] = (short)f2bf(acc[m][nf][0] + cst.x);
      ov[1] = (short)f2bf(acc[m][nf][1] + cst.y);
      ov[2] = (short)f2bf(acc[m][nf][2] + cst.z);
      ov[3] = (short)f2bf(acc[m][nf][3] + cst.w);
      int g2 = m * 2 + (g >> 1);
      int e0 = (g & 1) * 4;
      *(bf16x4v*)(gtn + (size_t)((sb * 2 + nf) * 4 + w) * 512 + l15 * 32 + g2 * 8 + e0) = ov;
    }
  }
}

// ---- Gram of G: fp32 LDS; 448 blocks x 112 s-rows. part[b][k1*128+k2], part[b][16384+k]=rowsum ----
__global__ __launch_bounds__(256) void gram(const unsigned short* __restrict__ GT,
                                            float* __restrict__ part) {
  __shared__ float lf[112 * 128];   // 57344 B
  int b = blockIdx.x, t = threadIdx.x;
  int k1b = t >> 4, k2b = t & 15;
  float acc[8][8];
  float gsum[8];
  #pragma unroll
  for (int i = 0; i < 8; i++) {
    gsum[i] = 0.f;
    #pragma unroll
    for (int j = 0; j < 8; j++) acc[i][j] = 0.f;
  }
  int St0 = b * 7;
  #pragma unroll
  for (int it = 0; it < 7; it++) {
    int u = t + 256 * it;              // 1792 16B-units
    int Stl = u >> 8, rem = u & 255;
    bf16x8 v = *(const bf16x8*)(GT + (size_t)(St0 + Stl) * 2048 + rem * 8);
    int sl = Stl * 16 + ((rem & 63) >> 2);
    int kk = (rem >> 6) * 32 + (rem & 3) * 8;
    float4 f0, f1;
    f0.x = bf2f((unsigned short)v[0]); f0.y = bf2f((unsigned short)v[1]);
    f0.z = bf2f((unsigned short)v[2]); f0.w = bf2f((unsigned short)v[3]);
    f1.x = bf2f((unsigned short)v[4]); f1.y = bf2f((unsigned short)v[5]);
    f1.z = bf2f((unsigned short)v[6]); f1.w = bf2f((unsigned short)v[7]);
    *(float4*)&lf[sl * 128 + kk] = f0;
    *(float4*)&lf[sl * 128 + kk + 4] = f1;
  }
  __syncthreads();
  for (int sl = 0; sl < 112; sl++) {
    float4 a0 = *(const float4*)&lf[sl * 128 + k1b * 8];
    float4 a1 = *(const float4*)&lf[sl * 128 + k1b * 8 + 4];
    float4 b0 = *(const float4*)&lf[sl * 128 + k2b * 8];
    float4 b1 = *(const float4*)&lf[sl * 128 + k2b * 8 + 4];
    float a[8]  = {a0.x, a0.y, a0.z, a0.w, a1.x, a1.y, a1.z, a1.w};
    float bb[8] = {b0.x, b0.y, b0.z, b0.w, b1.x, b1.y, b1.z, b1.w};
    #pragma unroll
    for (int i = 0; i < 8; i++)
      #pragma unroll
      for (int j = 0; j < 8; j++) acc[i][j] += a[i] * bb[j];
    if (k1b == 0) {
      #pragma unroll
      for (int j = 0; j < 8; j++) gsum[j] += bb[j];
    }
  }
  float* pb = part + (size_t)b * 16512;
  #pragma unroll
  for (int i = 0; i < 8; i++) {
    int k1 = k1b * 8 + i;
    *(float4*)(pb + k1 * 128 + k2b * 8)     = (float4){acc[i][0], acc[i][1], acc[i][2], acc[i][3]};
    *(float4*)(pb + k1 * 128 + k2b * 8 + 4) = (float4){acc[i][4], acc[i][5], acc[i][6], acc[i][7]};
  }
  if (k1b == 0) {
    *(float4*)(pb + 16384 + k2b * 8)     = (float4){gsum[0], gsum[1], gsum[2], gsum[3]};
    *(float4*)(pb + 16384 + k2b * 8 + 4) = (float4){gsum[4], gsum[5], gsum[6], gsum[7]};
  }
}

// ---- reduce 448 gram partials -> 4 partials ----
__global__ void gram_reduceA(const float* __restrict__ part, float* __restrict__ partB) {
  int e = blockIdx.x * 256 + threadIdx.x;
  if (e >= 16512) return;
  int p0 = blockIdx.y * 112;
  float s = 0.f;
  #pragma unroll 8
  for (int p = p0; p < p0 + 112; p++) s += part[(size_t)p * 16512 + e];
  partB[(size_t)blockIdx.y * 16512 + e] = s;
}

// ---- bn6 stats from 4 partB: a6[c], c6[c]. grid 128 x 256 (8 c per block) ----
__global__ __launch_bounds__(256) void bn6stats(
    const float* __restrict__ partB, const unsigned short* __restrict__ MtL,
    const float* __restrict__ g6, const float* __restrict__ b6,
    float* a6, float* c6) {
  __shared__ float covL[16384];   // 64 KB
  __shared__ float mL[8 * 128];
  __shared__ float gbL[128];
  int b = blockIdx.x, t = threadIdx.x;
  int c0 = b * 8;
  #pragma unroll
  for (int i = 0; i < 16; i++) {
    int u = (t + 256 * i) * 4;
    float4 va = *(const float4*)(partB + u);
    float4 vb = *(const float4*)(partB + 16512 + u);
    float4 vc = *(const float4*)(partB + 2 * 16512 + u);
    float4 vd = *(const float4*)(partB + 3 * 16512 + u);
    *(float4*)&covL[u] = (float4){va.x + vb.x + vc.x + vd.x, va.y + vb.y + vc.y + vd.y,
                                  va.z + vb.z + vc.z + vd.z, va.w + vb.w + vc.w + vd.w};
  }
  if (t < 128) {
    int row = t >> 4, unit = t & 15;
    bf16x8 v = *(const bf16x8*)(MtL + (size_t)(c0 + row) * KK + unit * 8);
    #pragma unroll
    for (int j = 0; j < 8; j++) mL[row * 128 + unit * 8 + j] = bf2f((unsigned short)v[j]);
  }
  if (t < 32) {
    int u = 16384 + t * 4;
    float4 va = *(const float4*)(partB + u);
    float4 vb = *(const float4*)(partB + 16512 + u);
    float4 vc = *(const float4*)(partB + 2 * 16512 + u);
    float4 vd = *(const float4*)(partB + 3 * 16512 + u);
    *(float4*)&gbL[t * 4] = (float4){va.x + vb.x + vc.x + vd.x, va.y + vb.y + vc.y + vd.y,
                                     va.z + vb.z + vc.z + vd.z, va.w + vb.w + vc.w + vd.w};
  }
  __syncthreads();
  int cl = t >> 5, kq = t & 31;
  float4 m4 = *(const float4*)&mL[cl * 128 + kq * 4];
  float4 g4 = *(const float4*)&gbL[kq * 4];
  float mv = m4.x * g4.x + m4.y * g4.y + m4.z * g4.z + m4.w * g4.w;
  float vv = 0.f;
  for (int k = 0; k < 128; k++) {
    float4 c4 = *(const float4*)&covL[k * 128 + kq * 4];
    float mk = mL[cl * 128 + k];
    vv += mk * (c4.x * m4.x + c4.y * m4.y + c4.z * m4.z + c4.w * m4.w);
  }
  for (int msk = 1; msk < 32; msk <<= 1) { mv += __shfl_xor(mv, msk); vv += __shfl_xor(vv, msk); }
  if (kq == 0) {
    int c = c0 + cl;
    float inv = 1.f / ((float)NB * SS);
    float mean = mv * inv, var = vv * inv - mean * mean;
    float r = rsqrtf(var + EPSV);
    float a = g6[c] * r;
    a6[c] = a; c6[c] = b6[c] - mean * a;
  }
}

// ---- GEMM2: XCD-swizzled 1D grid (3584); fused bn6 + LeakyReLU; nt fp32 out (r7-proven) ----
__global__ __launch_bounds__(256) void gemm2(
    const unsigned short* __restrict__ Mt, const unsigned short* __restrict__ GT,
    const float* __restrict__ a6, const float* __restrict__ c6,
    float* __restrict__ out) {
  // decode: all 8 ct-blocks of a (sb,n) pair share id%8 -> same XCD -> GT tile fetched once
  int id = blockIdx.x;
  int xcd = id & 7;
  int mid = id >> 3;          // 0..447
  int ct  = mid & 7;
  int p   = (mid >> 3) * 8 + xcd;   // pair 0..447
  int sb  = p % 14, n = p / 14;
  int t = threadIdx.x, w = t >> 6, lane = t & 63, g = lane >> 4, l15 = lane & 15;
  f32x4 acc[2][7];
  for (int m = 0; m < 2; m++)
    for (int nf = 0; nf < 7; nf++) acc[m][nf] = (f32x4){0.f, 0.f, 0.f, 0.f};
  int lofs = l15 * 32 + g * 8;
  const unsigned short* gtb = GT + (size_t)n * 200704;
  #pragma unroll
  for (int ks = 0; ks < 4; ks++) {
    bf16x8 af[2];
    #pragma unroll
    for (int m = 0; m < 2; m++)
      af[m] = *(const bf16x8*)(Mt + (size_t)((ct * 8 + w * 2 + m) * 4 + ks) * 512 + lofs);
    #pragma unroll
    for (int nf = 0; nf < 7; nf++) {
      bf16x8 bfr = *(const bf16x8*)(gtb + (size_t)((sb * 7 + nf) * 4 + ks) * 512 + lofs);
      #pragma unroll
      for (int m = 0; m < 2; m++)
        acc[m][nf] = __builtin_amdgcn_mfma_f32_16x16x32_bf16(af[m], bfr, acc[m][nf], 0, 0, 0);
    }
  }
  #pragma unroll
  for (int m = 0; m < 2; m++) {
    int cb = ct * 128 + w * 32 + m * 16 + g * 4;
    float4 av = *(const float4*)(a6 + cb);
    float4 cv = *(const float4*)(c6 + cb);
    #pragma unroll
    for (int nf = 0; nf < 7; nf++) {
      int s = sb * 112 + nf * 16 + l15;
      #pragma unroll
      for (int r = 0; r < 4; r++) {
        float a = (r == 0) ? av.x : (r == 1) ? av.y : (r == 2) ? av.z : av.w;
        float cc = (r == 0) ? cv.x : (r == 1) ? cv.y : (r == 2) ? cv.z : cv.w;
        float v = acc[m][nf][r] * a + cc;
        v = v >= 0.f ? v : 0.2f * v;
        __builtin_nontemporal_store(v, &out[((size_t)(n * CC + cb + r)) * SS + s]);
      }
    }
  }
}

extern "C" void kernel_launch(void* const* d_in, const int* in_sizes, int n_in,
                              void* d_out, int out_size, void* d_ws, size_t ws_size,
                              hipStream_t stream) {
  const float* x     = (const float*)d_in[0];
  const float* nodes = (const float*)d_in[1];
  const float* g1 = (const float*)d_in[2];
  const float* b1 = (const float*)d_in[3];
  const float* g2 = (const float*)d_in[4];
  const float* b2 = (const float*)d_in[5];
  const float* g3 = (const float*)d_in[6];
  const float* b3 = (const float*)d_in[7];
  const float* Wm = (const float*)d_in[8];
  const float* bW = (const float*)d_in[9];
  const float* loc = (const float*)d_in[10];
  const float* g6 = (const float*)d_in[11];
  const float* b6 = (const float*)d_in[12];
  float* out = (float*)d_out;
  char* ws = (char*)d_ws;

  float* p1s = (float*)(ws + 0);                           // 1,835,008
  float* p1q = (float*)(ws + 1835008);                     // 1,835,008
  float* a1  = (float*)(ws + 3670016);
  float* c1  = (float*)(ws + 3674112);
  float* Cst = (float*)(ws + 3678208);                     // 512 (pad 4096)
  unsigned short* nh   = (unsigned short*)(ws + 3682304);  // 262,144
  float* Lb  = (float*)(ws + 3944448);                     // 524,288
  unsigned short* ndA2 = (unsigned short*)(ws + 4468736);  // 262,144
  unsigned short* Mt   = (unsigned short*)(ws + 4730880);  // 262,144
  unsigned short* MtL  = (unsigned short*)(ws + 4993024);  // 262,144
  float* a6  = (float*)(ws + 5255168);
  float* c6  = (float*)(ws + 5259264);
  float* gramP = (float*)(ws + 5329920);                   // 448*16512*4 = 29,589,504
  unsigned short* GT = (unsigned short*)(ws + 34919424);   // 12,845,056
  unsigned short* xT = (unsigned short*)(ws + 47764480);   // 102,760,448
  float* partB = (float*)(ws + 150524928);                 // 264,192 -> end ~150.8 MB

  xpose_stats<<<dim3(14, 16, NB), dim3(512), 0, stream>>>(x, xT, p1s, p1q);
  prep_stats<<<dim3(160), dim3(256), 0, stream>>>(nodes, g2, b2, nh, p1s, p1q, g1, b1, a1, c1);
  linear_mfma<<<dim3(32, 2), dim3(256), 0, stream>>>(nh, Wm, bW, Lb);
  bn3_pack<<<dim3(KK), dim3(256), 0, stream>>>(Lb, g3, b3, loc, a1, c1, ndA2, Mt, MtL, Cst);
  gemm1<<<dim3(49, NB), dim3(256), 0, stream>>>(ndA2, xT, Cst, GT);
  gram<<<dim3(NSB3), dim3(256), 0, stream>>>(GT, gramP);
  gram_reduceA<<<dim3(65, 4), dim3(256), 0, stream>>>(gramP, partB);
  bn6stats<<<dim3(128), dim3(256), 0, stream>>>(partB, MtL, g6, b6, a6, c6);
  gemm2<<<dim3(3584), dim3(256), 0, stream>>>(Mt, GT, a6, c6, out);
}